// Round 1
// baseline (211.059 us; speedup 1.0000x reference)
//
#include <hip/hip_runtime.h>
#include <stdint.h>

#define NQQ 4096
#define NKK 4096
#define DIM 1024

typedef __attribute__((ext_vector_type(4))) float f32x4;
typedef __attribute__((ext_vector_type(8))) short bf16x8;

__device__ __forceinline__ float bf2f(ushort u) {
    union { uint32_t u; float f; } x; x.u = ((uint32_t)u) << 16; return x.f;
}
__device__ __forceinline__ ushort f2bf(float f) {
    union { float f; uint32_t u; } x; x.f = f;
    uint32_t u = x.u;
    return (ushort)((u + 0x7FFFu + ((u >> 16) & 1u)) >> 16);  // RNE
}

typedef const uint32_t __attribute__((address_space(1)))* as1_u32;
typedef uint32_t __attribute__((address_space(3)))* as3_u32;

__device__ __forceinline__ void load_lds16(const void* g, void* l) {
    __builtin_amdgcn_global_load_lds((as1_u32)(uintptr_t)g, (as3_u32)(uintptr_t)l, 16, 0, 0);
}

// ---------------- fp32 -> bf16 convert ----------------
__global__ void cvt_f32_bf16(const float* __restrict__ x, ushort* __restrict__ y, int n) {
    int i = (blockIdx.x * blockDim.x + threadIdx.x) * 4;
    if (i + 3 < n) {
        float4 v = *(const float4*)(x + i);
        ushort4 o;
        o.x = f2bf(v.x); o.y = f2bf(v.y); o.z = f2bf(v.z); o.w = f2bf(v.w);
        *(ushort4*)(y + i) = o;
    }
}

// ---------------- NT GEMM: C[i,j] = sum_k A[i,k]*B[j,k], m97-style ----------------
// EPI: 0 = +bias[j] -> bf16, 1 = exp(x*scale) -> bf16, 2 = fp32 raw
template <int EPI>
__device__ __forceinline__ void gemm_body(const ushort* __restrict__ A,
                                          const ushort* __restrict__ B,
                                          void* __restrict__ Cv,
                                          const float* __restrict__ bias,
                                          int N, int K, float scale,
                                          int bx, int by) {
    __shared__ ushort lA[128 * 32];
    __shared__ ushort lB[128 * 32];
    const int tid = threadIdx.x;
    const int wave = tid >> 6, lane = tid & 63;
    const int i0 = by * 128;
    const int j0 = bx * 128;
    const int wm = wave >> 1, wn = wave & 1;

    f32x4 acc[4][4];
    f32x4 zero = {0.f, 0.f, 0.f, 0.f};
#pragma unroll
    for (int m = 0; m < 4; m++)
#pragma unroll
        for (int n = 0; n < 4; n++) acc[m][n] = zero;

    // staging: 8 chunks of 1 KiB per tile; wave handles chunks {wave, wave+4}
    const int rs = wave * 16 + (lane >> 2);     // row within tile for chunk `wave`
    const int cbyte = (lane & 3) * 16;          // byte offset within 64-B row
    const char* gA1 = (const char*)(A + (size_t)(i0 + rs) * K) + cbyte;
    const char* gA2 = (const char*)(A + (size_t)(i0 + rs + 64) * K) + cbyte;
    const char* gB1 = (const char*)(B + (size_t)(j0 + rs) * K) + cbyte;
    const char* gB2 = (const char*)(B + (size_t)(j0 + rs + 64) * K) + cbyte;
    char* lA1 = (char*)lA + wave * 1024;
    char* lA2 = lA1 + 4096;
    char* lB1 = (char*)lB + wave * 1024;
    char* lB2 = lB1 + 4096;

    const int fr = lane & 15, fk = (lane >> 4) * 8;
    const ushort* pA = lA + (wm * 64 + fr) * 32 + fk;
    const ushort* pB = lB + (wn * 64 + fr) * 32 + fk;

    const int nk = K >> 5;
    for (int kt = 0; kt < nk; ++kt) {
        load_lds16(gA1, lA1);
        load_lds16(gA2, lA2);
        load_lds16(gB1, lB1);
        load_lds16(gB2, lB2);
        gA1 += 64; gA2 += 64; gB1 += 64; gB2 += 64;
        __syncthreads();
        bf16x8 af[4], bv[4];
#pragma unroll
        for (int m = 0; m < 4; m++) af[m] = *(const bf16x8*)(pA + m * 16 * 32);
#pragma unroll
        for (int n = 0; n < 4; n++) bv[n] = *(const bf16x8*)(pB + n * 16 * 32);
#pragma unroll
        for (int m = 0; m < 4; m++)
#pragma unroll
            for (int n = 0; n < 4; n++)
                acc[m][n] = __builtin_amdgcn_mfma_f32_16x16x32_bf16(af[m], bv[n], acc[m][n], 0, 0, 0);
        __syncthreads();
    }

    const int fq = lane >> 4;
    const int r0 = i0 + wm * 64, c0 = j0 + wn * 64;
#pragma unroll
    for (int m = 0; m < 4; m++)
#pragma unroll
        for (int n = 0; n < 4; n++) {
            const int c = c0 + n * 16 + fr;
            const float badd = (EPI == 0) ? bias[c] : 0.0f;
#pragma unroll
            for (int vv = 0; vv < 4; ++vv) {
                const int r = r0 + m * 16 + fq * 4 + vv;
                const float x = acc[m][n][vv];
                if (EPI == 0)
                    ((ushort*)Cv)[(size_t)r * N + c] = f2bf(x + badd);
                else if (EPI == 1)
                    ((ushort*)Cv)[(size_t)r * N + c] = f2bf(__expf(x * scale));
                else
                    ((float*)Cv)[(size_t)r * N + c] = x;
            }
        }
}

__global__ __launch_bounds__(256) void gemm_proj(
    const ushort* qb, const ushort* kb, const ushort* vb,
    const ushort* wq, const ushort* wk, const ushort* wv,
    const float* bq, const float* bk, const float* bv,
    ushort* Qp, ushort* Kp, ushort* Vp) {
    const ushort* A; const ushort* B; const float* bias; ushort* C;
    if (blockIdx.z == 0)      { A = qb; B = wq; bias = bq; C = Qp; }
    else if (blockIdx.z == 1) { A = kb; B = wk; bias = bk; C = Kp; }
    else                      { A = vb; B = wv; bias = bv; C = Vp; }
    gemm_body<0>(A, B, C, bias, DIM, DIM, 1.0f, blockIdx.x, blockIdx.y);
}

__global__ __launch_bounds__(256) void gemm_scores(const ushort* Qp, const ushort* Kp, ushort* E) {
    gemm_body<1>(Qp, Kp, E, nullptr, NKK, DIM, 1.0f / 4096.0f, blockIdx.x, blockIdx.y);
}

__global__ __launch_bounds__(256) void gemm_out(const ushort* E, const ushort* Vt, float* out) {
    gemm_body<2>(E, Vt, out, nullptr, DIM, NKK, 1.0f, blockIdx.x, blockIdx.y);
}

// ---------------- column softmax denominators ----------------
// E is [NQQ][NKK] bf16; colsum[j] = sum_i E[i][j]; 64-row partials then combine.
__global__ void colsum_partial(const ushort* __restrict__ E, float* __restrict__ part) {
    const int c0 = blockIdx.x * 1024 + threadIdx.x * 4;
    const int r0 = blockIdx.y * 64;
    float s0 = 0, s1 = 0, s2 = 0, s3 = 0;
    for (int r = 0; r < 64; ++r) {
        ushort4 e = *(const ushort4*)(E + (size_t)(r0 + r) * NKK + c0);
        s0 += bf2f(e.x); s1 += bf2f(e.y); s2 += bf2f(e.z); s3 += bf2f(e.w);
    }
    float4 o = {s0, s1, s2, s3};
    *(float4*)(part + (size_t)blockIdx.y * NKK + c0) = o;
}

__global__ void colsum_combine(const float* __restrict__ part, float* __restrict__ cinv) {
    const int j = blockIdx.x * 256 + threadIdx.x;
    float s = 0;
    for (int c = 0; c < 64; ++c) s += part[(size_t)c * NKK + j];
    cinv[j] = 1.0f / s;
}

// ---------------- V'[j,d] = Vp[j,d] * cinv[j], transposed into Vt[d][j] ----------------
__global__ void scale_transpose(const ushort* __restrict__ Vp, const float* __restrict__ cinv,
                                ushort* __restrict__ Vt) {
    __shared__ ushort t[64][66];
    const int j0 = blockIdx.x * 64, d0 = blockIdx.y * 64;
    const int c = threadIdx.x & 63, rb = threadIdx.x >> 6;
#pragma unroll
    for (int i = 0; i < 16; ++i) {
        const int r = i * 4 + rb;
        const float inv = cinv[j0 + r];
        t[r][c] = f2bf(bf2f(Vp[(size_t)(j0 + r) * DIM + d0 + c]) * inv);
    }
    __syncthreads();
#pragma unroll
    for (int i = 0; i < 16; ++i) {
        const int r = i * 4 + rb;  // r indexes d, c indexes j now
        Vt[(size_t)(d0 + r) * NKK + j0 + c] = t[c][r];
    }
}

extern "C" void kernel_launch(void* const* d_in, const int* in_sizes, int n_in,
                              void* d_out, int out_size, void* d_ws, size_t ws_size,
                              hipStream_t stream) {
    const float* q  = (const float*)d_in[0];
    const float* k  = (const float*)d_in[1];
    const float* v  = (const float*)d_in[2];
    const float* Wq = (const float*)d_in[3];
    const float* bq = (const float*)d_in[4];
    const float* Wk = (const float*)d_in[5];
    const float* bk = (const float*)d_in[6];
    const float* Wv = (const float*)d_in[7];
    const float* bv = (const float*)d_in[8];
    float* out = (float*)d_out;

    char* ws = (char*)d_ws;
    size_t off = 0;
    auto alloc = [&](size_t b) { char* p = ws + off; off += (b + 255) & ~(size_t)255; return p; };
    ushort* qb  = (ushort*)alloc((size_t)NQQ * DIM * 2);
    ushort* kb  = (ushort*)alloc((size_t)NKK * DIM * 2);
    ushort* vb  = (ushort*)alloc((size_t)NKK * DIM * 2);
    ushort* wqb = (ushort*)alloc((size_t)DIM * DIM * 2);
    ushort* wkb = (ushort*)alloc((size_t)DIM * DIM * 2);
    ushort* wvb = (ushort*)alloc((size_t)DIM * DIM * 2);
    ushort* Qp  = (ushort*)alloc((size_t)NQQ * DIM * 2);
    ushort* Kp  = (ushort*)alloc((size_t)NKK * DIM * 2);
    ushort* Vp  = (ushort*)alloc((size_t)NKK * DIM * 2);
    ushort* E   = (ushort*)alloc((size_t)NQQ * NKK * 2);
    float*  part = (float*)alloc((size_t)64 * NKK * 4);
    float*  cinv = (float*)alloc((size_t)NKK * 4);
    ushort* Vt  = (ushort*)alloc((size_t)DIM * NKK * 2);
    (void)ws_size; (void)in_sizes; (void)n_in; (void)out_size;

    const int nqd = NQQ * DIM;       // 4194304
    const int ndd = DIM * DIM;       // 1048576
    cvt_f32_bf16<<<nqd / 1024, 256, 0, stream>>>(q, qb, nqd);
    cvt_f32_bf16<<<nqd / 1024, 256, 0, stream>>>(k, kb, nqd);
    cvt_f32_bf16<<<nqd / 1024, 256, 0, stream>>>(v, vb, nqd);
    cvt_f32_bf16<<<ndd / 1024, 256, 0, stream>>>(Wq, wqb, ndd);
    cvt_f32_bf16<<<ndd / 1024, 256, 0, stream>>>(Wk, wkb, ndd);
    cvt_f32_bf16<<<ndd / 1024, 256, 0, stream>>>(Wv, wvb, ndd);

    gemm_proj<<<dim3(DIM / 128, NQQ / 128, 3), 256, 0, stream>>>(
        qb, kb, vb, wqb, wkb, wvb, bq, bk, bv, Qp, Kp, Vp);

    gemm_scores<<<dim3(NKK / 128, NQQ / 128), 256, 0, stream>>>(Qp, Kp, E);

    colsum_partial<<<dim3(NKK / 1024, 64), 256, 0, stream>>>(E, part);
    colsum_combine<<<NKK / 256, 256, 0, stream>>>(part, cinv);

    scale_transpose<<<dim3(NKK / 64, DIM / 64), 256, 0, stream>>>(Vp, cinv, Vt);

    gemm_out<<<dim3(DIM / 128, NQQ / 128), 256, 0, stream>>>(E, Vt, out);
}

// Round 2
// 188.521 us; speedup vs baseline: 1.1196x; 1.1196x over previous
//
#include <hip/hip_runtime.h>
#include <stdint.h>

#define NQQ 4096
#define NKK 4096
#define DIM 1024

typedef __attribute__((ext_vector_type(4))) float f32x4;
typedef __attribute__((ext_vector_type(8))) short bf16x8;

__device__ __forceinline__ float bf2f(ushort u) {
    union { uint32_t u; float f; } x; x.u = ((uint32_t)u) << 16; return x.f;
}
__device__ __forceinline__ ushort f2bf(float f) {
    union { float f; uint32_t u; } x; x.f = f;
    uint32_t u = x.u;
    return (ushort)((u + 0x7FFFu + ((u >> 16) & 1u)) >> 16);  // RNE
}

typedef const uint32_t __attribute__((address_space(1)))* as1_u32;
typedef uint32_t __attribute__((address_space(3)))* as3_u32;

__device__ __forceinline__ void load_lds16(const void* g, void* l) {
    __builtin_amdgcn_global_load_lds((as1_u32)(uintptr_t)g, (as3_u32)(uintptr_t)l, 16, 0, 0);
}

// ---------------- fused fp32 -> bf16 convert (3 arrays per launch) ----------------
__global__ void cvt3_f32_bf16(const float* __restrict__ a, const float* __restrict__ b,
                              const float* __restrict__ c,
                              ushort* __restrict__ oa, ushort* __restrict__ ob,
                              ushort* __restrict__ oc, int n) {
    const float* x; ushort* y;
    if (blockIdx.z == 0)      { x = a; y = oa; }
    else if (blockIdx.z == 1) { x = b; y = ob; }
    else                      { x = c; y = oc; }
    int i = (blockIdx.x * blockDim.x + threadIdx.x) * 4;
    if (i + 3 < n) {
        float4 v = *(const float4*)(x + i);
        ushort4 o;
        o.x = f2bf(v.x); o.y = f2bf(v.y); o.z = f2bf(v.z); o.w = f2bf(v.w);
        *(ushort4*)(y + i) = o;
    }
}

// ---------------- NT GEMM: C[i,j] = sum_k A[i,k]*B[j,k], m97-style ----------------
// EPI: 0 = +bias[j] -> bf16, 1 = exp(x*scale) -> bf16, 2 = fp32 raw
// Kstride = row stride of A and B (elements); nk = number of K=32 steps.
template <int EPI>
__device__ __forceinline__ void gemm_body(const ushort* __restrict__ A,
                                          const ushort* __restrict__ B,
                                          void* __restrict__ Cv,
                                          const float* __restrict__ bias,
                                          int N, int Kstride, int nk, float scale,
                                          int bx, int by) {
    __shared__ ushort lA[128 * 32];
    __shared__ ushort lB[128 * 32];
    const int tid = threadIdx.x;
    const int wave = tid >> 6, lane = tid & 63;
    const int i0 = by * 128;
    const int j0 = bx * 128;
    const int wm = wave >> 1, wn = wave & 1;

    f32x4 acc[4][4];
    f32x4 zero = {0.f, 0.f, 0.f, 0.f};
#pragma unroll
    for (int m = 0; m < 4; m++)
#pragma unroll
        for (int n = 0; n < 4; n++) acc[m][n] = zero;

    // staging: 8 chunks of 1 KiB per tile; wave handles chunks {wave, wave+4}
    const int rs = wave * 16 + (lane >> 2);     // row within tile for chunk `wave`
    const int cbyte = (lane & 3) * 16;          // byte offset within 64-B row
    const char* gA1 = (const char*)(A + (size_t)(i0 + rs) * Kstride) + cbyte;
    const char* gA2 = (const char*)(A + (size_t)(i0 + rs + 64) * Kstride) + cbyte;
    const char* gB1 = (const char*)(B + (size_t)(j0 + rs) * Kstride) + cbyte;
    const char* gB2 = (const char*)(B + (size_t)(j0 + rs + 64) * Kstride) + cbyte;
    char* lA1 = (char*)lA + wave * 1024;
    char* lA2 = lA1 + 4096;
    char* lB1 = (char*)lB + wave * 1024;
    char* lB2 = lB1 + 4096;

    const int fr = lane & 15, fk = (lane >> 4) * 8;
    const ushort* pA = lA + (wm * 64 + fr) * 32 + fk;
    const ushort* pB = lB + (wn * 64 + fr) * 32 + fk;

    for (int kt = 0; kt < nk; ++kt) {
        load_lds16(gA1, lA1);
        load_lds16(gA2, lA2);
        load_lds16(gB1, lB1);
        load_lds16(gB2, lB2);
        gA1 += 64; gA2 += 64; gB1 += 64; gB2 += 64;
        __syncthreads();
        bf16x8 af[4], bv[4];
#pragma unroll
        for (int m = 0; m < 4; m++) af[m] = *(const bf16x8*)(pA + m * 16 * 32);
#pragma unroll
        for (int n = 0; n < 4; n++) bv[n] = *(const bf16x8*)(pB + n * 16 * 32);
#pragma unroll
        for (int m = 0; m < 4; m++)
#pragma unroll
            for (int n = 0; n < 4; n++)
                acc[m][n] = __builtin_amdgcn_mfma_f32_16x16x32_bf16(af[m], bv[n], acc[m][n], 0, 0, 0);
        __syncthreads();
    }

    const int fq = lane >> 4;
    const int r0 = i0 + wm * 64, c0 = j0 + wn * 64;
#pragma unroll
    for (int m = 0; m < 4; m++)
#pragma unroll
        for (int n = 0; n < 4; n++) {
            const int c = c0 + n * 16 + fr;
            const float badd = (EPI == 0) ? bias[c] : 0.0f;
#pragma unroll
            for (int vv = 0; vv < 4; ++vv) {
                const int r = r0 + m * 16 + fq * 4 + vv;
                const float x = acc[m][n][vv];
                if (EPI == 0)
                    ((ushort*)Cv)[(size_t)r * N + c] = f2bf(x + badd);
                else if (EPI == 1)
                    ((ushort*)Cv)[(size_t)r * N + c] = f2bf(__expf(x * scale));
                else
                    ((float*)Cv)[(size_t)r * N + c] = x;
            }
        }
}

__global__ __launch_bounds__(256) void gemm_proj(
    const ushort* qb, const ushort* kb, const ushort* vb,
    const ushort* wq, const ushort* wk, const ushort* wv,
    const float* bq, const float* bk, const float* bv,
    ushort* Qp, ushort* Kp, ushort* Vp) {
    const ushort* A; const ushort* B; const float* bias; ushort* C;
    if (blockIdx.z == 0)      { A = qb; B = wq; bias = bq; C = Qp; }
    else if (blockIdx.z == 1) { A = kb; B = wk; bias = bk; C = Kp; }
    else                      { A = vb; B = wv; bias = bv; C = Vp; }
    gemm_body<0>(A, B, C, bias, DIM, DIM, DIM / 32, 1.0f, blockIdx.x, blockIdx.y);
}

__global__ __launch_bounds__(256) void gemm_scores(const ushort* Qp, const ushort* Kp, ushort* E) {
    gemm_body<1>(Qp, Kp, E, nullptr, NKK, DIM, DIM / 32, 1.0f / 4096.0f, blockIdx.x, blockIdx.y);
}

// split-K final GEMM: out_partial[s] = E[:, ks..ke] @ Vt[:, ks..ke]^T
// K split over 128 k-steps: 43 / 43 / 42
__global__ __launch_bounds__(256) void gemm_out_split(const ushort* __restrict__ E,
                                                      const ushort* __restrict__ Vt,
                                                      float* __restrict__ partial) {
    const int s = blockIdx.z;
    const int kstep0 = s * 43;                 // k-steps before this split
    const int nk = (s == 2) ? 42 : 43;
    const int k0 = kstep0 * 32;                // element offset
    float* C = partial + (size_t)s * NQQ * DIM;
    gemm_body<2>(E + k0, Vt + k0, C, nullptr, DIM, NKK, nk, 1.0f, blockIdx.x, blockIdx.y);
}

__global__ void reduce3(const float* __restrict__ p, float* __restrict__ out) {
    const size_t stride = (size_t)NQQ * DIM;
    const size_t i = ((size_t)blockIdx.x * 256 + threadIdx.x) * 4;
    float4 a = *(const float4*)(p + i);
    float4 b = *(const float4*)(p + stride + i);
    float4 c = *(const float4*)(p + 2 * stride + i);
    float4 o;
    o.x = a.x + b.x + c.x;
    o.y = a.y + b.y + c.y;
    o.z = a.z + b.z + c.z;
    o.w = a.w + b.w + c.w;
    *(float4*)(out + i) = o;
}

// ---------------- column softmax denominators ----------------
__global__ void colsum_partial(const ushort* __restrict__ E, float* __restrict__ part) {
    const int c0 = blockIdx.x * 1024 + threadIdx.x * 4;
    const int r0 = blockIdx.y * 64;
    float s0 = 0, s1 = 0, s2 = 0, s3 = 0;
    for (int r = 0; r < 64; ++r) {
        ushort4 e = *(const ushort4*)(E + (size_t)(r0 + r) * NKK + c0);
        s0 += bf2f(e.x); s1 += bf2f(e.y); s2 += bf2f(e.z); s3 += bf2f(e.w);
    }
    float4 o = {s0, s1, s2, s3};
    *(float4*)(part + (size_t)blockIdx.y * NKK + c0) = o;
}

__global__ void colsum_combine(const float* __restrict__ part, float* __restrict__ cinv) {
    const int j = blockIdx.x * 256 + threadIdx.x;
    float s = 0;
    for (int c = 0; c < 64; ++c) s += part[(size_t)c * NKK + j];
    cinv[j] = 1.0f / s;
}

// ---------------- V'[j,d] = Vp[j,d] * cinv[j], transposed into Vt[d][j] ----------------
__global__ void scale_transpose(const ushort* __restrict__ Vp, const float* __restrict__ cinv,
                                ushort* __restrict__ Vt) {
    __shared__ ushort t[64][66];
    const int j0 = blockIdx.x * 64, d0 = blockIdx.y * 64;
    const int c = threadIdx.x & 63, rb = threadIdx.x >> 6;
#pragma unroll
    for (int i = 0; i < 16; ++i) {
        const int r = i * 4 + rb;
        const float inv = cinv[j0 + r];
        t[r][c] = f2bf(bf2f(Vp[(size_t)(j0 + r) * DIM + d0 + c]) * inv);
    }
    __syncthreads();
#pragma unroll
    for (int i = 0; i < 16; ++i) {
        const int r = i * 4 + rb;  // r indexes d, c indexes j now
        Vt[(size_t)(d0 + r) * NKK + j0 + c] = t[c][r];
    }
}

extern "C" void kernel_launch(void* const* d_in, const int* in_sizes, int n_in,
                              void* d_out, int out_size, void* d_ws, size_t ws_size,
                              hipStream_t stream) {
    const float* q  = (const float*)d_in[0];
    const float* k  = (const float*)d_in[1];
    const float* v  = (const float*)d_in[2];
    const float* Wq = (const float*)d_in[3];
    const float* bq = (const float*)d_in[4];
    const float* Wk = (const float*)d_in[5];
    const float* bk = (const float*)d_in[6];
    const float* Wv = (const float*)d_in[7];
    const float* bv = (const float*)d_in[8];
    float* out = (float*)d_out;

    char* ws = (char*)d_ws;
    size_t off = 0;
    auto alloc = [&](size_t b) { char* p = ws + off; off += (b + 255) & ~(size_t)255; return p; };
    // persistent region (live until the end)
    ushort* E    = (ushort*)alloc((size_t)NQQ * NKK * 2);       // 32 MB
    ushort* Vt   = (ushort*)alloc((size_t)DIM * NKK * 2);       //  8 MB
    float*  part = (float*)alloc((size_t)64 * NKK * 4);         //  1 MB
    float*  cinv = (float*)alloc((size_t)NKK * 4);
    // temp region — dead before gemm_out_split; aliased by `partial` (48 MB)
    char* tempBase = ws + off;
    ushort* qb  = (ushort*)alloc((size_t)NQQ * DIM * 2);        //  8 MB
    ushort* kb  = (ushort*)alloc((size_t)NKK * DIM * 2);        //  8 MB
    ushort* vb  = (ushort*)alloc((size_t)NKK * DIM * 2);        //  8 MB
    ushort* wqb = (ushort*)alloc((size_t)DIM * DIM * 2);        //  2 MB
    ushort* wkb = (ushort*)alloc((size_t)DIM * DIM * 2);        //  2 MB
    ushort* wvb = (ushort*)alloc((size_t)DIM * DIM * 2);        //  2 MB
    ushort* Qp  = (ushort*)alloc((size_t)NQQ * DIM * 2);        //  8 MB
    ushort* Kp  = (ushort*)alloc((size_t)NKK * DIM * 2);        //  8 MB
    ushort* Vp  = (ushort*)alloc((size_t)NKK * DIM * 2);        //  8 MB  (sum 54 MB)
    float* partial = (float*)tempBase;                          // 3 * 16 MB = 48 MB alias
    (void)ws_size; (void)in_sizes; (void)n_in; (void)out_size;

    const int nqd = NQQ * DIM;       // 4194304
    const int ndd = DIM * DIM;       // 1048576
    cvt3_f32_bf16<<<dim3(nqd / 1024, 1, 3), 256, 0, stream>>>(q, k, v, qb, kb, vb, nqd);
    cvt3_f32_bf16<<<dim3(ndd / 1024, 1, 3), 256, 0, stream>>>(Wq, Wk, Wv, wqb, wkb, wvb, ndd);

    gemm_proj<<<dim3(DIM / 128, NQQ / 128, 3), 256, 0, stream>>>(
        qb, kb, vb, wqb, wkb, wvb, bq, bk, bv, Qp, Kp, Vp);

    gemm_scores<<<dim3(NKK / 128, NQQ / 128), 256, 0, stream>>>(Qp, Kp, E);

    colsum_partial<<<dim3(NKK / 1024, 64), 256, 0, stream>>>(E, part);
    colsum_combine<<<NKK / 256, 256, 0, stream>>>(part, cinv);

    scale_transpose<<<dim3(NKK / 64, DIM / 64), 256, 0, stream>>>(Vp, cinv, Vt);

    gemm_out_split<<<dim3(DIM / 128, NQQ / 128, 3), 256, 0, stream>>>(E, Vt, partial);

    reduce3<<<nqd / 1024, 256, 0, stream>>>(partial, out);
}

// Round 3
// 175.724 us; speedup vs baseline: 1.2011x; 1.0728x over previous
//
#include <hip/hip_runtime.h>
#include <stdint.h>

#define NQQ 4096
#define NKK 4096
#define DIM 1024

typedef __attribute__((ext_vector_type(4))) float f32x4;
typedef __attribute__((ext_vector_type(8))) short bf16x8;

__device__ __forceinline__ float bf2f(ushort u) {
    union { uint32_t u; float f; } x; x.u = ((uint32_t)u) << 16; return x.f;
}
__device__ __forceinline__ ushort f2bf(float f) {
    union { float f; uint32_t u; } x; x.f = f;
    uint32_t u = x.u;
    return (ushort)((u + 0x7FFFu + ((u >> 16) & 1u)) >> 16);  // RNE
}

typedef const uint32_t __attribute__((address_space(1)))* as1_u32;
typedef uint32_t __attribute__((address_space(3)))* as3_u32;

__device__ __forceinline__ void load_lds16(const void* g, void* l) {
    __builtin_amdgcn_global_load_lds((as1_u32)(uintptr_t)g, (as3_u32)(uintptr_t)l, 16, 0, 0);
}

// XCD-aware chunked swizzle (bijective: nwg % 8 == 0 in all uses).
// Consecutive logical ids land on the SAME XCD -> L2 panel reuse.
__device__ __forceinline__ int xcd_swizzle(int orig, int nwg) {
    const int q = nwg >> 3;
    return (orig & 7) * q + (orig >> 3);
}

// ---------------- fused fp32 -> bf16 convert (3 arrays per launch) ----------------
__global__ void cvt3_f32_bf16(const float* __restrict__ a, const float* __restrict__ b,
                              const float* __restrict__ c,
                              ushort* __restrict__ oa, ushort* __restrict__ ob,
                              ushort* __restrict__ oc, int n) {
    const float* x; ushort* y;
    if (blockIdx.z == 0)      { x = a; y = oa; }
    else if (blockIdx.z == 1) { x = b; y = ob; }
    else                      { x = c; y = oc; }
    int i = (blockIdx.x * blockDim.x + threadIdx.x) * 4;
    if (i + 3 < n) {
        float4 v = *(const float4*)(x + i);
        ushort4 o;
        o.x = f2bf(v.x); o.y = f2bf(v.y); o.z = f2bf(v.z); o.w = f2bf(v.w);
        *(ushort4*)(y + i) = o;
    }
}

// ---------------- NT GEMM: C[i,j] = sum_k A[i,k]*B[j,k], m97-style ----------------
// EPI: 0 = +bias[j] -> bf16, 1 = exp(x*scale) -> bf16 + per-block column sums, 2 = fp32 raw
template <int EPI>
__device__ __forceinline__ void gemm_body(const ushort* __restrict__ A,
                                          const ushort* __restrict__ B,
                                          void* __restrict__ Cv,
                                          const float* __restrict__ bias,
                                          float* __restrict__ cs,
                                          int N, int Kstride, int nk, float scale,
                                          int bx, int by) {
    __shared__ ushort lA[128 * 32];
    __shared__ ushort lB[128 * 32];
    __shared__ float csum[2][128];
    const int tid = threadIdx.x;
    const int wave = tid >> 6, lane = tid & 63;
    const int i0 = by * 128;
    const int j0 = bx * 128;
    const int wm = wave >> 1, wn = wave & 1;

    f32x4 acc[4][4];
    f32x4 zero = {0.f, 0.f, 0.f, 0.f};
#pragma unroll
    for (int m = 0; m < 4; m++)
#pragma unroll
        for (int n = 0; n < 4; n++) acc[m][n] = zero;

    // staging: 8 chunks of 1 KiB per tile; wave handles chunks {wave, wave+4}
    const int rs = wave * 16 + (lane >> 2);     // row within tile for chunk `wave`
    const int cbyte = (lane & 3) * 16;          // byte offset within 64-B row
    const char* gA1 = (const char*)(A + (size_t)(i0 + rs) * Kstride) + cbyte;
    const char* gA2 = (const char*)(A + (size_t)(i0 + rs + 64) * Kstride) + cbyte;
    const char* gB1 = (const char*)(B + (size_t)(j0 + rs) * Kstride) + cbyte;
    const char* gB2 = (const char*)(B + (size_t)(j0 + rs + 64) * Kstride) + cbyte;
    char* lA1 = (char*)lA + wave * 1024;
    char* lA2 = lA1 + 4096;
    char* lB1 = (char*)lB + wave * 1024;
    char* lB2 = lB1 + 4096;

    const int fr = lane & 15, fk = (lane >> 4) * 8;
    const ushort* pA = lA + (wm * 64 + fr) * 32 + fk;
    const ushort* pB = lB + (wn * 64 + fr) * 32 + fk;

    for (int kt = 0; kt < nk; ++kt) {
        load_lds16(gA1, lA1);
        load_lds16(gA2, lA2);
        load_lds16(gB1, lB1);
        load_lds16(gB2, lB2);
        gA1 += 64; gA2 += 64; gB1 += 64; gB2 += 64;
        __syncthreads();
        bf16x8 af[4], bv[4];
#pragma unroll
        for (int m = 0; m < 4; m++) af[m] = *(const bf16x8*)(pA + m * 16 * 32);
#pragma unroll
        for (int n = 0; n < 4; n++) bv[n] = *(const bf16x8*)(pB + n * 16 * 32);
#pragma unroll
        for (int m = 0; m < 4; m++)
#pragma unroll
            for (int n = 0; n < 4; n++)
                acc[m][n] = __builtin_amdgcn_mfma_f32_16x16x32_bf16(af[m], bv[n], acc[m][n], 0, 0, 0);
        __syncthreads();
    }

    const int fq = lane >> 4;
    const int r0 = i0 + wm * 64, c0 = j0 + wn * 64;

    if (EPI == 1) {
        float cp[4] = {0.f, 0.f, 0.f, 0.f};
#pragma unroll
        for (int m = 0; m < 4; m++)
#pragma unroll
            for (int n = 0; n < 4; n++) {
                const int c = c0 + n * 16 + fr;
#pragma unroll
                for (int vv = 0; vv < 4; ++vv) {
                    const int r = r0 + m * 16 + fq * 4 + vv;
                    const ushort ue = f2bf(__expf(acc[m][n][vv] * scale));
                    ((ushort*)Cv)[(size_t)r * N + c] = ue;
                    cp[n] += bf2f(ue);
                }
            }
        // reduce over fq (lanes fr, fr+16, fr+32, fr+48)
#pragma unroll
        for (int n = 0; n < 4; n++) {
            float s = cp[n];
            s += __shfl_xor(s, 16);
            s += __shfl_xor(s, 32);
            if (fq == 0) csum[wm][wn * 64 + n * 16 + fr] = s;
        }
        __syncthreads();
        if (tid < 128)
            cs[(size_t)by * NKK + j0 + tid] = csum[0][tid] + csum[1][tid];
    } else {
#pragma unroll
        for (int m = 0; m < 4; m++)
#pragma unroll
            for (int n = 0; n < 4; n++) {
                const int c = c0 + n * 16 + fr;
                const float badd = (EPI == 0) ? bias[c] : 0.0f;
#pragma unroll
                for (int vv = 0; vv < 4; ++vv) {
                    const int r = r0 + m * 16 + fq * 4 + vv;
                    const float x = acc[m][n][vv];
                    if (EPI == 0)
                        ((ushort*)Cv)[(size_t)r * N + c] = f2bf(x + badd);
                    else
                        ((float*)Cv)[(size_t)r * N + c] = x;
                }
            }
    }
}

__global__ __launch_bounds__(256) void gemm_proj(
    const ushort* qb, const ushort* kb, const ushort* vb,
    const ushort* wq, const ushort* wk, const ushort* wv,
    const float* bq, const float* bk, const float* bv,
    ushort* Qp, ushort* Kp, ushort* Vp) {
    const ushort* A; const ushort* B; const float* bias; ushort* C;
    if (blockIdx.z == 0)      { A = qb; B = wq; bias = bq; C = Qp; }
    else if (blockIdx.z == 1) { A = kb; B = wk; bias = bk; C = Kp; }
    else                      { A = vb; B = wv; bias = bv; C = Vp; }
    const int lg = xcd_swizzle(blockIdx.x, 256);
    gemm_body<0>(A, B, C, bias, nullptr, DIM, DIM, DIM / 32, 1.0f, lg & 7, lg >> 3);
}

__global__ __launch_bounds__(256) void gemm_scores(const ushort* Qp, const ushort* Kp,
                                                   ushort* E, float* cpart) {
    const int lg = xcd_swizzle(blockIdx.x, 1024);
    gemm_body<1>(Qp, Kp, E, nullptr, cpart, NKK, DIM, DIM / 32, 1.0f / 4096.0f,
                 lg & 31, lg >> 5);
}

// split-K(4) final GEMM; split 0 writes directly to d_out, splits 1..3 to partial.
__global__ __launch_bounds__(256) void gemm_out_split(const ushort* __restrict__ E,
                                                      const ushort* __restrict__ Vt,
                                                      float* __restrict__ out,
                                                      float* __restrict__ partial) {
    const int s = blockIdx.z;
    const int k0 = s * 1024;                   // 32 k-steps per split
    float* C = (s == 0) ? out : (partial + (size_t)(s - 1) * NQQ * DIM);
    const int lg = xcd_swizzle(blockIdx.x, 256);
    gemm_body<2>(E + k0, Vt + k0, C, nullptr, nullptr, DIM, NKK, 32, 1.0f,
                 lg & 7, lg >> 3);
}

__global__ void reduce_add3(const float* __restrict__ p, float* __restrict__ out) {
    const size_t stride = (size_t)NQQ * DIM;
    const size_t i = ((size_t)blockIdx.x * 256 + threadIdx.x) * 4;
    float4 o = *(const float4*)(out + i);
    float4 a = *(const float4*)(p + i);
    float4 b = *(const float4*)(p + stride + i);
    float4 c = *(const float4*)(p + 2 * stride + i);
    o.x += a.x + b.x + c.x;
    o.y += a.y + b.y + c.y;
    o.z += a.z + b.z + c.z;
    o.w += a.w + b.w + c.w;
    *(float4*)(out + i) = o;
}

// combine the 32 per-block-row column-sum partials into 1/colsum
__global__ void colsum_combine(const float* __restrict__ cpart, float* __restrict__ cinv) {
    const int j = blockIdx.x * 256 + threadIdx.x;
    float s = 0;
    for (int c = 0; c < 32; ++c) s += cpart[(size_t)c * NKK + j];
    cinv[j] = 1.0f / s;
}

// ---------------- V'[j,d] = Vp[j,d] * cinv[j], transposed into Vt[d][j] ----------------
__global__ void scale_transpose(const ushort* __restrict__ Vp, const float* __restrict__ cinv,
                                ushort* __restrict__ Vt) {
    __shared__ ushort t[64][66];
    const int j0 = blockIdx.x * 64, d0 = blockIdx.y * 64;
    const int c = threadIdx.x & 63, rb = threadIdx.x >> 6;
#pragma unroll
    for (int i = 0; i < 16; ++i) {
        const int r = i * 4 + rb;
        const float inv = cinv[j0 + r];
        t[r][c] = f2bf(bf2f(Vp[(size_t)(j0 + r) * DIM + d0 + c]) * inv);
    }
    __syncthreads();
#pragma unroll
    for (int i = 0; i < 16; ++i) {
        const int r = i * 4 + rb;  // r indexes d, c indexes j now
        Vt[(size_t)(d0 + r) * NKK + j0 + c] = t[c][r];
    }
}

extern "C" void kernel_launch(void* const* d_in, const int* in_sizes, int n_in,
                              void* d_out, int out_size, void* d_ws, size_t ws_size,
                              hipStream_t stream) {
    const float* q  = (const float*)d_in[0];
    const float* k  = (const float*)d_in[1];
    const float* v  = (const float*)d_in[2];
    const float* Wq = (const float*)d_in[3];
    const float* bq = (const float*)d_in[4];
    const float* Wk = (const float*)d_in[5];
    const float* bk = (const float*)d_in[6];
    const float* Wv = (const float*)d_in[7];
    const float* bv = (const float*)d_in[8];
    float* out = (float*)d_out;

    char* ws = (char*)d_ws;
    size_t off = 0;
    auto alloc = [&](size_t b) { char* p = ws + off; off += (b + 255) & ~(size_t)255; return p; };
    // persistent region (live until the end)
    ushort* E     = (ushort*)alloc((size_t)NQQ * NKK * 2);      // 32 MB
    ushort* Vt    = (ushort*)alloc((size_t)DIM * NKK * 2);      //  8 MB
    float*  cpart = (float*)alloc((size_t)32 * NKK * 4);        //  0.5 MB
    float*  cinv  = (float*)alloc((size_t)NKK * 4);
    // temp region — dead before gemm_out_split; aliased by `partial` (48 MB)
    char* tempBase = ws + off;
    ushort* qb  = (ushort*)alloc((size_t)NQQ * DIM * 2);        //  8 MB
    ushort* kb  = (ushort*)alloc((size_t)NKK * DIM * 2);        //  8 MB
    ushort* vb  = (ushort*)alloc((size_t)NKK * DIM * 2);        //  8 MB
    ushort* wqb = (ushort*)alloc((size_t)DIM * DIM * 2);        //  2 MB
    ushort* wkb = (ushort*)alloc((size_t)DIM * DIM * 2);        //  2 MB
    ushort* wvb = (ushort*)alloc((size_t)DIM * DIM * 2);        //  2 MB
    ushort* Qp  = (ushort*)alloc((size_t)NQQ * DIM * 2);        //  8 MB
    ushort* Kp  = (ushort*)alloc((size_t)NKK * DIM * 2);        //  8 MB
    ushort* Vp  = (ushort*)alloc((size_t)NKK * DIM * 2);        //  8 MB  (sum 54 MB)
    float* partial = (float*)tempBase;                          // 3 * 16 MB = 48 MB alias
    (void)ws_size; (void)in_sizes; (void)n_in; (void)out_size;

    const int nqd = NQQ * DIM;       // 4194304
    const int ndd = DIM * DIM;       // 1048576
    cvt3_f32_bf16<<<dim3(nqd / 1024, 1, 3), 256, 0, stream>>>(q, k, v, qb, kb, vb, nqd);
    cvt3_f32_bf16<<<dim3(ndd / 1024, 1, 3), 256, 0, stream>>>(Wq, Wk, Wv, wqb, wkb, wvb, ndd);

    gemm_proj<<<dim3(256, 1, 3), 256, 0, stream>>>(
        qb, kb, vb, wqb, wkb, wvb, bq, bk, bv, Qp, Kp, Vp);

    gemm_scores<<<dim3(1024, 1, 1), 256, 0, stream>>>(Qp, Kp, E, cpart);

    colsum_combine<<<NKK / 256, 256, 0, stream>>>(cpart, cinv);

    scale_transpose<<<dim3(NKK / 64, DIM / 64), 256, 0, stream>>>(Vp, cinv, Vt);

    gemm_out_split<<<dim3(256, 1, 4), 256, 0, stream>>>(E, Vt, out, partial);

    reduce_add3<<<nqd / 1024, 256, 0, stream>>>(partial, out);
}

// Round 5
// 168.742 us; speedup vs baseline: 1.2508x; 1.0414x over previous
//
#include <hip/hip_runtime.h>
#include <stdint.h>

#define NQQ 4096
#define NKK 4096
#define DIM 1024

typedef __attribute__((ext_vector_type(4))) float f32x4;
typedef __attribute__((ext_vector_type(8))) short bf16x8;

__device__ __forceinline__ float bf2f(ushort u) {
    union { uint32_t u; float f; } x; x.u = ((uint32_t)u) << 16; return x.f;
}
__device__ __forceinline__ ushort f2bf(float f) {
    union { float f; uint32_t u; } x; x.f = f;
    uint32_t u = x.u;
    return (ushort)((u + 0x7FFFu + ((u >> 16) & 1u)) >> 16);  // RNE
}

typedef const uint32_t __attribute__((address_space(1)))* as1_u32;
typedef uint32_t __attribute__((address_space(3)))* as3_u32;

__device__ __forceinline__ void load_lds16(const void* g, void* l) {
    __builtin_amdgcn_global_load_lds((as1_u32)(uintptr_t)g, (as3_u32)(uintptr_t)l, 16, 0, 0);
}

// XCD-aware chunked swizzle (bijective: nwg % 8 == 0 in all uses).
__device__ __forceinline__ int xcd_swizzle(int orig, int nwg) {
    const int q = nwg >> 3;
    return (orig & 7) * q + (orig >> 3);
}

// ---------------- fused fp32 -> bf16 convert (3 arrays per launch) ----------------
__global__ void cvt3_f32_bf16(const float* __restrict__ a, const float* __restrict__ b,
                              const float* __restrict__ c,
                              ushort* __restrict__ oa, ushort* __restrict__ ob,
                              ushort* __restrict__ oc, int n) {
    const float* x; ushort* y;
    if (blockIdx.z == 0)      { x = a; y = oa; }
    else if (blockIdx.z == 1) { x = b; y = ob; }
    else                      { x = c; y = oc; }
    int i = (blockIdx.x * blockDim.x + threadIdx.x) * 4;
    if (i + 3 < n) {
        float4 v = *(const float4*)(x + i);
        ushort4 o;
        o.x = f2bf(v.x); o.y = f2bf(v.y); o.z = f2bf(v.z); o.w = f2bf(v.w);
        *(ushort4*)(y + i) = o;
    }
}

// ================= 256x256 8-phase GEMM template (NT kernel) =================
// C[i,j] = sum_k A[i,k]*B[j,k].  BK=64, 8 waves (2M x 4N), 2-deep LDS dbuf,
// st_16x32 XOR swizzle, counted vmcnt, setprio around MFMA.
// EPI: 1 = exp(x*scale)->bf16 + column sums, 2 = fp32 raw.
// LDS: 131072 bytes; csum (EPI=1) reuses the first 2 KiB after the K-loop.
template <int EPI>
__device__ __forceinline__ void gemm8_body(const ushort* __restrict__ A,
                                           const ushort* __restrict__ B,
                                           void* __restrict__ Cv,
                                           float* __restrict__ cs,
                                           int N, int Kstride, int NT, size_t k0e,
                                           float scale, int i0, int j0, int csrow) {
    extern __shared__ char sm[];   // 131072
    const int tid = threadIdx.x;
    const int w = tid >> 6, l = tid & 63;
    const int wm = w >> 2, wn = w & 3;            // 2M x 4N waves
    const int fr = l & 15, fq = l >> 4;
    const size_t KB = (size_t)Kstride * 2;        // row stride bytes

    // swizzled read offset (lane-const): byte = row*128 + fq*16, ^32 if row bit2
    const int aoff = (fr * 128 + fq * 16) ^ ((l & 4) << 3);
    // stage lane constants: rows 16w+(l>>3)(+8); inverse-swizzled source col
    const int stRow = (w << 4) + (l >> 3);
    const int stColByte = ((l & 7) << 4) ^ (((l >> 5) & 1) << 5);

    f32x4 acc[8][4];
    f32x4 zero = {0.f, 0.f, 0.f, 0.f};
#pragma unroll
    for (int m = 0; m < 8; ++m)
#pragma unroll
        for (int n = 0; n < 4; ++n) acc[m][n] = zero;

    const char* Ab = (const char*)A;
    const char* Bb = (const char*)B;

    // stage one half-tile (ab: 0=A 1=B, h: half) of K-tile t into buffer buf
    auto stage = [&](int buf, int ab, int h, int t) {
        const char* src = ab ? Bb : Ab;
        const int rb = ab ? j0 : i0;
        const char* g = src + (size_t)(rb + h * 128 + stRow) * KB
                        + (k0e + (size_t)t * 64) * 2 + stColByte;
        char* d = sm + buf * 65536 + ab * 32768 + h * 16384 + (w * 2) * 1024;
        load_lds16(g, d);
        load_lds16(g + 8 * KB, d + 1024);
    };

    // prologue: tile0 all 4 halves + tile1.A0 + tile1.B1
    stage(0, 0, 0, 0); stage(0, 0, 1, 0); stage(0, 1, 0, 0); stage(0, 1, 1, 0);
    stage(1, 0, 0, 1); stage(1, 1, 1, 1);
    asm volatile("s_waitcnt vmcnt(4)" ::: "memory");   // tile0 landed; 2 half-tiles in flight
    __builtin_amdgcn_s_barrier();

    auto phase = [&](int buf, int rh, int ch, bool doStage, int sbuf, int sab, int sh, int st) {
        const char* baA = sm + buf * 65536 + rh * 16384 + wm * 8192 + aoff;
        const char* baB = sm + buf * 65536 + 32768 + ch * 16384 + wn * 4096 + aoff;
        bf16x8 a[4][2], b[2][2];
#pragma unroll
        for (int m = 0; m < 4; ++m)
#pragma unroll
            for (int ks = 0; ks < 2; ++ks)
                a[m][ks] = *(const bf16x8*)(baA + m * 2048 + ks * 64);
#pragma unroll
        for (int n = 0; n < 2; ++n)
#pragma unroll
            for (int ks = 0; ks < 2; ++ks)
                b[n][ks] = *(const bf16x8*)(baB + n * 2048 + ks * 64);
        if (doStage) stage(sbuf, sab, sh, st);
        __builtin_amdgcn_s_barrier();
        asm volatile("s_waitcnt lgkmcnt(0)" ::: "memory");
        __builtin_amdgcn_sched_barrier(0);
        __builtin_amdgcn_s_setprio(1);
#pragma unroll
        for (int m = 0; m < 4; ++m)
#pragma unroll
            for (int n = 0; n < 2; ++n)
#pragma unroll
                for (int ks = 0; ks < 2; ++ks)
                    acc[rh * 4 + m][ch * 2 + n] = __builtin_amdgcn_mfma_f32_16x16x32_bf16(
                        a[m][ks], b[n][ks], acc[rh * 4 + m][ch * 2 + n], 0, 0, 0);
        __builtin_amdgcn_s_setprio(0);
    };

    // main loop: phases (0,0) (0,1) (1,1) (1,0); stages: t+1.A1, t+1.B0, t+2.A0, t+2.B1
    for (int t = 0; t < NT; ++t) {
        const int buf = t & 1;
        const bool s1 = (t + 1) < NT, s2 = (t + 2) < NT;
        phase(buf, 0, 0, s1, buf ^ 1, 0, 1, t + 1);
        __builtin_amdgcn_s_barrier();
        phase(buf, 0, 1, s1, buf ^ 1, 1, 0, t + 1);
        __builtin_amdgcn_s_barrier();
        phase(buf, 1, 1, s2, buf,     0, 0, t + 2);
        __builtin_amdgcn_s_barrier();
        phase(buf, 1, 0, s2, buf,     1, 1, t + 2);
        if (t < NT - 2)       asm volatile("s_waitcnt vmcnt(4)" ::: "memory");
        else if (t == NT - 2) asm volatile("s_waitcnt vmcnt(0)" ::: "memory");
        __builtin_amdgcn_s_barrier();
    }

    // ---------------- epilogue ----------------
    if (EPI == 1) {
        float* csum = (float*)sm;   // LDS free after final loop barrier
        ushort* E = (ushort*)Cv;
        float cp[4] = {0.f, 0.f, 0.f, 0.f};
#pragma unroll
        for (int mi = 0; mi < 8; ++mi) {
            const int rg = i0 + (mi >> 2) * 128 + wm * 64 + (mi & 3) * 16 + fq * 4;
#pragma unroll
            for (int ni = 0; ni < 4; ++ni) {
                const int cg = j0 + (ni >> 1) * 128 + wn * 32 + (ni & 1) * 16 + fr;
#pragma unroll
                for (int r = 0; r < 4; ++r) {
                    const ushort ue = f2bf(__expf(acc[mi][ni][r] * scale));
                    E[(size_t)(rg + r) * N + cg] = ue;
                    cp[ni] += bf2f(ue);
                }
            }
        }
#pragma unroll
        for (int ni = 0; ni < 4; ++ni) {
            float s = cp[ni];
            s += __shfl_xor(s, 16);
            s += __shfl_xor(s, 32);
            if (fq == 0)
                csum[wm * 256 + (ni >> 1) * 128 + wn * 32 + (ni & 1) * 16 + fr] = s;
        }
        __syncthreads();
        if (tid < 256)
            cs[(size_t)csrow * NKK + j0 + tid] = csum[tid] + csum[256 + tid];
    } else {
        float* O = (float*)Cv;
#pragma unroll
        for (int mi = 0; mi < 8; ++mi) {
            const int rg = i0 + (mi >> 2) * 128 + wm * 64 + (mi & 3) * 16 + fq * 4;
#pragma unroll
            for (int ni = 0; ni < 4; ++ni) {
                const int cg = j0 + (ni >> 1) * 128 + wn * 32 + (ni & 1) * 16 + fr;
#pragma unroll
                for (int r = 0; r < 4; ++r)
                    O[(size_t)(rg + r) * N + cg] = acc[mi][ni][r];
            }
        }
    }
}

__global__ __launch_bounds__(512, 2) void gemm8_scores(const ushort* __restrict__ Qp,
                                                       const ushort* __restrict__ Kp,
                                                       ushort* __restrict__ E,
                                                       float* __restrict__ cpart) {
    const int b = xcd_swizzle(blockIdx.x, 256);
    const int tx = b & 15, ty = b >> 4;
    gemm8_body<1>(Qp, Kp, E, cpart, NKK, DIM, 16, 0, 1.0f / 4096.0f,
                  ty * 256, tx * 256, ty);
}

__global__ __launch_bounds__(512, 2) void gemm8_out(const ushort* __restrict__ E,
                                                    const ushort* __restrict__ Vt,
                                                    float* __restrict__ out,
                                                    float* __restrict__ partial) {
    const int s = blockIdx.z;
    float* C = (s == 0) ? out : (partial + (size_t)(s - 1) * NQQ * DIM);
    const int b = xcd_swizzle(blockIdx.x, 64);
    const int tx = b & 3, ty = b >> 2;
    gemm8_body<2>(E, Vt, C, nullptr, DIM, NKK, 16, (size_t)s * 1024, 1.0f,
                  ty * 256, tx * 256, 0);
}

// ---------------- projection GEMM (m97 128^2 structure, bias epilogue) ----------------
__device__ __forceinline__ void gemm_proj_body(const ushort* __restrict__ A,
                                               const ushort* __restrict__ B,
                                               ushort* __restrict__ C,
                                               const float* __restrict__ bias,
                                               int N, int K, int bx, int by) {
    __shared__ ushort lA[128 * 32];
    __shared__ ushort lB[128 * 32];
    const int tid = threadIdx.x;
    const int wave = tid >> 6, lane = tid & 63;
    const int i0 = by * 128, j0 = bx * 128;
    const int wm = wave >> 1, wn = wave & 1;

    f32x4 acc[4][4];
    f32x4 zero = {0.f, 0.f, 0.f, 0.f};
#pragma unroll
    for (int m = 0; m < 4; m++)
#pragma unroll
        for (int n = 0; n < 4; n++) acc[m][n] = zero;

    const int rs = wave * 16 + (lane >> 2);
    const int cbyte = (lane & 3) * 16;
    const char* gA1 = (const char*)(A + (size_t)(i0 + rs) * K) + cbyte;
    const char* gA2 = (const char*)(A + (size_t)(i0 + rs + 64) * K) + cbyte;
    const char* gB1 = (const char*)(B + (size_t)(j0 + rs) * K) + cbyte;
    const char* gB2 = (const char*)(B + (size_t)(j0 + rs + 64) * K) + cbyte;
    char* lA1 = (char*)lA + wave * 1024;
    char* lA2 = lA1 + 4096;
    char* lB1 = (char*)lB + wave * 1024;
    char* lB2 = lB1 + 4096;

    const int fr = lane & 15, fk = (lane >> 4) * 8;
    const ushort* pA = lA + (wm * 64 + fr) * 32 + fk;
    const ushort* pB = lB + (wn * 64 + fr) * 32 + fk;

    for (int kt = 0; kt < K / 32; ++kt) {
        load_lds16(gA1, lA1);
        load_lds16(gA2, lA2);
        load_lds16(gB1, lB1);
        load_lds16(gB2, lB2);
        gA1 += 64; gA2 += 64; gB1 += 64; gB2 += 64;
        __syncthreads();
        bf16x8 af[4], bv[4];
#pragma unroll
        for (int m = 0; m < 4; m++) af[m] = *(const bf16x8*)(pA + m * 16 * 32);
#pragma unroll
        for (int n = 0; n < 4; n++) bv[n] = *(const bf16x8*)(pB + n * 16 * 32);
#pragma unroll
        for (int m = 0; m < 4; m++)
#pragma unroll
            for (int n = 0; n < 4; n++)
                acc[m][n] = __builtin_amdgcn_mfma_f32_16x16x32_bf16(af[m], bv[n], acc[m][n], 0, 0, 0);
        __syncthreads();
    }

    const int fq = lane >> 4;
    const int r0 = i0 + wm * 64, c0 = j0 + wn * 64;
#pragma unroll
    for (int m = 0; m < 4; m++)
#pragma unroll
        for (int n = 0; n < 4; n++) {
            const int c = c0 + n * 16 + fr;
            const float badd = bias[c];
#pragma unroll
            for (int vv = 0; vv < 4; ++vv) {
                const int r = r0 + m * 16 + fq * 4 + vv;
                C[(size_t)r * N + c] = f2bf(acc[m][n][vv] + badd);
            }
        }
}

__global__ __launch_bounds__(256) void gemm_proj(
    const ushort* qb, const ushort* kb, const ushort* vb,
    const ushort* wq, const ushort* wk, const ushort* wv,
    const float* bq, const float* bk, const float* bv,
    ushort* Qp, ushort* Kp, ushort* Vp) {
    const ushort* A; const ushort* B; const float* bias; ushort* C;
    if (blockIdx.z == 0)      { A = qb; B = wq; bias = bq; C = Qp; }
    else if (blockIdx.z == 1) { A = kb; B = wk; bias = bk; C = Kp; }
    else                      { A = vb; B = wv; bias = bv; C = Vp; }
    const int lg = xcd_swizzle(blockIdx.x, 256);
    gemm_proj_body(A, B, C, bias, DIM, DIM, lg & 7, lg >> 3);
}

// ---------------- small fixup kernels ----------------
__global__ void reduce_add3(const float* __restrict__ p, float* __restrict__ out) {
    const size_t stride = (size_t)NQQ * DIM;
    const size_t i = ((size_t)blockIdx.x * 256 + threadIdx.x) * 4;
    float4 o = *(const float4*)(out + i);
    float4 a = *(const float4*)(p + i);
    float4 b = *(const float4*)(p + stride + i);
    float4 c = *(const float4*)(p + 2 * stride + i);
    o.x += a.x + b.x + c.x;
    o.y += a.y + b.y + c.y;
    o.z += a.z + b.z + c.z;
    o.w += a.w + b.w + c.w;
    *(float4*)(out + i) = o;
}

__global__ void colsum_combine(const float* __restrict__ cpart, float* __restrict__ cinv) {
    const int j = blockIdx.x * 256 + threadIdx.x;
    float s = 0;
    for (int c = 0; c < 16; ++c) s += cpart[(size_t)c * NKK + j];
    cinv[j] = 1.0f / s;
}

__global__ void scale_transpose(const ushort* __restrict__ Vp, const float* __restrict__ cinv,
                                ushort* __restrict__ Vt) {
    __shared__ ushort t[64][66];
    const int j0 = blockIdx.x * 64, d0 = blockIdx.y * 64;
    const int c = threadIdx.x & 63, rb = threadIdx.x >> 6;
#pragma unroll
    for (int i = 0; i < 16; ++i) {
        const int r = i * 4 + rb;
        const float inv = cinv[j0 + r];
        t[r][c] = f2bf(bf2f(Vp[(size_t)(j0 + r) * DIM + d0 + c]) * inv);
    }
    __syncthreads();
#pragma unroll
    for (int i = 0; i < 16; ++i) {
        const int r = i * 4 + rb;
        Vt[(size_t)(d0 + r) * NKK + j0 + c] = t[c][r];
    }
}

extern "C" void kernel_launch(void* const* d_in, const int* in_sizes, int n_in,
                              void* d_out, int out_size, void* d_ws, size_t ws_size,
                              hipStream_t stream) {
    const float* q  = (const float*)d_in[0];
    const float* k  = (const float*)d_in[1];
    const float* v  = (const float*)d_in[2];
    const float* Wq = (const float*)d_in[3];
    const float* bq = (const float*)d_in[4];
    const float* Wk = (const float*)d_in[5];
    const float* bk = (const float*)d_in[6];
    const float* Wv = (const float*)d_in[7];
    const float* bv = (const float*)d_in[8];
    float* out = (float*)d_out;

    char* ws = (char*)d_ws;
    size_t off = 0;
    auto alloc = [&](size_t b) { char* p = ws + off; off += (b + 255) & ~(size_t)255; return p; };
    // persistent region
    ushort* E     = (ushort*)alloc((size_t)NQQ * NKK * 2);      // 32 MB
    ushort* Vt    = (ushort*)alloc((size_t)DIM * NKK * 2);      //  8 MB
    float*  cpart = (float*)alloc((size_t)16 * NKK * 4);        // 256 KB
    float*  cinv  = (float*)alloc((size_t)NKK * 4);
    // temp region (dead before gemm8_out) aliased by `partial`
    char* tempBase = ws + off;
    ushort* qb  = (ushort*)alloc((size_t)NQQ * DIM * 2);
    ushort* kb  = (ushort*)alloc((size_t)NKK * DIM * 2);
    ushort* vb  = (ushort*)alloc((size_t)NKK * DIM * 2);
    ushort* wqb = (ushort*)alloc((size_t)DIM * DIM * 2);
    ushort* wkb = (ushort*)alloc((size_t)DIM * DIM * 2);
    ushort* wvb = (ushort*)alloc((size_t)DIM * DIM * 2);
    ushort* Qp  = (ushort*)alloc((size_t)NQQ * DIM * 2);
    ushort* Kp  = (ushort*)alloc((size_t)NKK * DIM * 2);
    ushort* Vp  = (ushort*)alloc((size_t)NKK * DIM * 2);
    float* partial = (float*)tempBase;                          // 48 MB alias
    (void)ws_size; (void)in_sizes; (void)n_in; (void)out_size;

    const int SMEM = 131072;
    hipFuncSetAttribute((const void*)gemm8_scores, hipFuncAttributeMaxDynamicSharedMemorySize, SMEM);
    hipFuncSetAttribute((const void*)gemm8_out, hipFuncAttributeMaxDynamicSharedMemorySize, SMEM);

    const int nqd = NQQ * DIM;
    const int ndd = DIM * DIM;
    cvt3_f32_bf16<<<dim3(nqd / 1024, 1, 3), 256, 0, stream>>>(q, k, v, qb, kb, vb, nqd);
    cvt3_f32_bf16<<<dim3(ndd / 1024, 1, 3), 256, 0, stream>>>(Wq, Wk, Wv, wqb, wkb, wvb, ndd);

    gemm_proj<<<dim3(256, 1, 3), 256, 0, stream>>>(
        qb, kb, vb, wqb, wkb, wvb, bq, bk, bv, Qp, Kp, Vp);

    gemm8_scores<<<dim3(256), 512, SMEM, stream>>>(Qp, Kp, E, cpart);

    colsum_combine<<<NKK / 256, 256, 0, stream>>>(cpart, cinv);

    scale_transpose<<<dim3(NKK / 64, DIM / 64), 256, 0, stream>>>(Vp, cinv, Vt);

    gemm8_out<<<dim3(64, 1, 4), 512, SMEM, stream>>>(E, Vt, out, partial);

    reduce_add3<<<nqd / 1024, 256, 0, stream>>>(partial, out);
}

// Round 6
// 148.163 us; speedup vs baseline: 1.4245x; 1.1389x over previous
//
#include <hip/hip_runtime.h>
#include <stdint.h>

#define NQQ 4096
#define NKK 4096
#define DIM 1024

typedef __attribute__((ext_vector_type(4))) float f32x4;
typedef __attribute__((ext_vector_type(8))) short bf16x8;

__device__ __forceinline__ float bf2f(ushort u) {
    union { uint32_t u; float f; } x; x.u = ((uint32_t)u) << 16; return x.f;
}
__device__ __forceinline__ ushort f2bf(float f) {
    union { float f; uint32_t u; } x; x.f = f;
    uint32_t u = x.u;
    return (ushort)((u + 0x7FFFu + ((u >> 16) & 1u)) >> 16);  // RNE
}

typedef const uint32_t __attribute__((address_space(1)))* as1_u32;
typedef uint32_t __attribute__((address_space(3)))* as3_u32;

__device__ __forceinline__ void load_lds16(const void* g, void* l) {
    __builtin_amdgcn_global_load_lds((as1_u32)(uintptr_t)g, (as3_u32)(uintptr_t)l, 16, 0, 0);
}

// XCD-aware chunked swizzle (bijective: nwg % 8 == 0 in all uses).
__device__ __forceinline__ int xcd_swizzle(int orig, int nwg) {
    const int q = nwg >> 3;
    return (orig & 7) * q + (orig >> 3);
}

// ---------------- fused fp32 -> bf16 convert (3 arrays per launch) ----------------
__global__ void cvt3_f32_bf16(const float* __restrict__ a, const float* __restrict__ b,
                              const float* __restrict__ c,
                              ushort* __restrict__ oa, ushort* __restrict__ ob,
                              ushort* __restrict__ oc, int n) {
    const float* x; ushort* y;
    if (blockIdx.z == 0)      { x = a; y = oa; }
    else if (blockIdx.z == 1) { x = b; y = ob; }
    else                      { x = c; y = oc; }
    int i = (blockIdx.x * blockDim.x + threadIdx.x) * 4;
    if (i + 3 < n) {
        float4 v = *(const float4*)(x + i);
        ushort4 o;
        o.x = f2bf(v.x); o.y = f2bf(v.y); o.z = f2bf(v.z); o.w = f2bf(v.w);
        *(ushort4*)(y + i) = o;
    }
}

// ================= 256x256 8-phase GEMM template (NT kernel) =================
// C[i,j] = sum_k A[i,k]*B[j,k].  BK=64, 8 waves (2M x 4N), 2-deep LDS dbuf,
// 3-bit 16B-granule XOR swizzle (element (R,k) stored at byte
// R*128 + ((2k) ^ ((R&7)<<4))), frag-caching across phases, counted vmcnt,
// setprio around MFMA.  LDS: 131072 bytes; csum (EPI=1) reuses sm after loop.
// EPI: 1 = exp(x*scale)->bf16 + column sums, 2 = fp32 raw.
template <int EPI>
__device__ __forceinline__ void gemm8_body(const ushort* __restrict__ A,
                                           const ushort* __restrict__ B,
                                           void* __restrict__ Cv,
                                           float* __restrict__ cs,
                                           int N, int Kstride, int NT, size_t k0e,
                                           float scale, int i0, int j0, int csrow) {
    extern __shared__ char sm[];   // 131072
    const int tid = threadIdx.x;
    const int w = tid >> 6, l = tid & 63;
    const int wm = w >> 2, wn = w & 3;            // 2M x 4N waves
    const int fr = l & 15, fq = l >> 4;
    const size_t KB = (size_t)Kstride * 2;        // row stride bytes

    // swizzled read offset: row fr (+16m), col byte (fq*16 ^ (row&7)*16) [^ ks*64]
    const int aoff = fr * 128 + ((fq * 16) ^ ((l & 7) * 16));
    // stage lane constants: rows 16w+(l>>3)(+8); inverse-swizzled source col
    const int stRow = (w << 4) + (l >> 3);
    const int stColByte = ((l & 7) ^ (l >> 3)) << 4;

    f32x4 acc[8][4];
    f32x4 zero = {0.f, 0.f, 0.f, 0.f};
#pragma unroll
    for (int m = 0; m < 8; ++m)
#pragma unroll
        for (int n = 0; n < 4; ++n) acc[m][n] = zero;

    const char* Ab = (const char*)A;
    const char* Bb = (const char*)B;

    // stage one half-tile (ab: 0=A 1=B, h: half) of K-tile t into buffer buf
    auto stage = [&](int buf, int ab, int h, int t) {
        const char* src = ab ? Bb : Ab;
        const int rb = ab ? j0 : i0;
        const char* g = src + (size_t)(rb + h * 128 + stRow) * KB
                        + (k0e + (size_t)t * 64) * 2 + stColByte;
        char* d = sm + buf * 65536 + ab * 32768 + h * 16384 + (w * 2) * 1024;
        load_lds16(g, d);
        load_lds16(g + 8 * KB, d + 1024);
    };

    // prologue: tile0 all 4 halves + tile1.A0 + tile1.B1
    stage(0, 0, 0, 0); stage(0, 0, 1, 0); stage(0, 1, 0, 0); stage(0, 1, 1, 0);
    stage(1, 0, 0, 1); stage(1, 1, 1, 1);
    asm volatile("s_waitcnt vmcnt(4)" ::: "memory");   // tile0 landed; 2 half-tiles in flight
    __builtin_amdgcn_s_barrier();

    bf16x8 ar[4][2];   // cached A frags for current rh (2 phases)
    bf16x8 br[2][2];   // cached B frags for current ch

    auto phase = [&](int buf, int rh, int ch, bool rdA, bool rdB,
                     bool doStage, int sbuf, int sab, int sh, int st) {
        if (rdA) {
            const char* baA = sm + buf * 65536 + rh * 16384 + wm * 8192;
#pragma unroll
            for (int m = 0; m < 4; ++m)
#pragma unroll
                for (int ks = 0; ks < 2; ++ks)
                    ar[m][ks] = *(const bf16x8*)(baA + m * 2048 + (aoff ^ (ks * 64)));
        }
        if (rdB) {
            const char* baB = sm + buf * 65536 + 32768 + ch * 16384 + wn * 4096;
#pragma unroll
            for (int n = 0; n < 2; ++n)
#pragma unroll
                for (int ks = 0; ks < 2; ++ks)
                    br[n][ks] = *(const bf16x8*)(baB + n * 2048 + (aoff ^ (ks * 64)));
        }
        if (doStage) stage(sbuf, sab, sh, st);
        __builtin_amdgcn_s_barrier();
        asm volatile("s_waitcnt lgkmcnt(0)" ::: "memory");
        __builtin_amdgcn_sched_barrier(0);
        __builtin_amdgcn_s_setprio(1);
#pragma unroll
        for (int m = 0; m < 4; ++m)
#pragma unroll
            for (int n = 0; n < 2; ++n)
#pragma unroll
                for (int ks = 0; ks < 2; ++ks)
                    acc[rh * 4 + m][ch * 2 + n] = __builtin_amdgcn_mfma_f32_16x16x32_bf16(
                        ar[m][ks], br[n][ks], acc[rh * 4 + m][ch * 2 + n], 0, 0, 0);
        __builtin_amdgcn_s_setprio(0);
    };

    // phases (0,0)(0,1)(1,1)(1,0); A read once per rh, B read per ch change;
    // stages: t+1.A1, t+1.B0, t+2.A0, t+2.B1 (slots provably drained — see audit)
    for (int t = 0; t < NT; ++t) {
        const int buf = t & 1;
        const bool s1 = (t + 1) < NT, s2 = (t + 2) < NT;
        phase(buf, 0, 0, true,  true,  s1, buf ^ 1, 0, 1, t + 1);
        __builtin_amdgcn_s_barrier();
        phase(buf, 0, 1, false, true,  s1, buf ^ 1, 1, 0, t + 1);
        __builtin_amdgcn_s_barrier();
        phase(buf, 1, 1, true,  false, s2, buf,     0, 0, t + 2);
        __builtin_amdgcn_s_barrier();
        phase(buf, 1, 0, false, true,  s2, buf,     1, 1, t + 2);
        if (t < NT - 2)       asm volatile("s_waitcnt vmcnt(4)" ::: "memory");
        else if (t == NT - 2) asm volatile("s_waitcnt vmcnt(0)" ::: "memory");
        __builtin_amdgcn_s_barrier();
    }

    // ---------------- epilogue ----------------
    if (EPI == 1) {
        float* csum = (float*)sm;   // LDS free after final loop barrier
        ushort* E = (ushort*)Cv;
        float cp[4] = {0.f, 0.f, 0.f, 0.f};
#pragma unroll
        for (int mi = 0; mi < 8; ++mi) {
            const int rg = i0 + (mi >> 2) * 128 + wm * 64 + (mi & 3) * 16 + fq * 4;
#pragma unroll
            for (int ni = 0; ni < 4; ++ni) {
                const int cg = j0 + (ni >> 1) * 128 + wn * 32 + (ni & 1) * 16 + fr;
#pragma unroll
                for (int r = 0; r < 4; ++r) {
                    const ushort ue = f2bf(__expf(acc[mi][ni][r] * scale));
                    E[(size_t)(rg + r) * N + cg] = ue;
                    cp[ni] += bf2f(ue);
                }
            }
        }
#pragma unroll
        for (int ni = 0; ni < 4; ++ni) {
            float s = cp[ni];
            s += __shfl_xor(s, 16);
            s += __shfl_xor(s, 32);
            if (fq == 0)
                csum[wm * 256 + (ni >> 1) * 128 + wn * 32 + (ni & 1) * 16 + fr] = s;
        }
        __syncthreads();
        if (tid < 256)
            cs[(size_t)csrow * NKK + j0 + tid] = csum[tid] + csum[256 + tid];
    } else {
        float* O = (float*)Cv;
#pragma unroll
        for (int mi = 0; mi < 8; ++mi) {
            const int rg = i0 + (mi >> 2) * 128 + wm * 64 + (mi & 3) * 16 + fq * 4;
#pragma unroll
            for (int ni = 0; ni < 4; ++ni) {
                const int cg = j0 + (ni >> 1) * 128 + wn * 32 + (ni & 1) * 16 + fr;
#pragma unroll
                for (int r = 0; r < 4; ++r)
                    O[(size_t)(rg + r) * N + cg] = acc[mi][ni][r];
            }
        }
    }
}

__global__ __launch_bounds__(512, 2) void gemm8_scores(const ushort* __restrict__ Qp,
                                                       const ushort* __restrict__ Kp,
                                                       ushort* __restrict__ E,
                                                       float* __restrict__ cpart) {
    const int b = xcd_swizzle(blockIdx.x, 256);
    const int tx = b & 15, ty = b >> 4;
    gemm8_body<1>(Qp, Kp, E, cpart, NKK, DIM, 16, 0, 1.0f / 4096.0f,
                  ty * 256, tx * 256, ty);
}

__global__ __launch_bounds__(512, 2) void gemm8_out(const ushort* __restrict__ E,
                                                    const ushort* __restrict__ Vt,
                                                    float* __restrict__ out,
                                                    float* __restrict__ partial) {
    const int s = blockIdx.z;
    float* C = (s == 0) ? out : (partial + (size_t)(s - 1) * NQQ * DIM);
    const int b = xcd_swizzle(blockIdx.x, 64);
    const int tx = b & 3, ty = b >> 2;
    gemm8_body<2>(E, Vt, C, nullptr, DIM, NKK, 16, (size_t)s * 1024, 1.0f,
                  ty * 256, tx * 256, 0);
}

// ---------------- projection GEMM (m97 128^2 structure, bias epilogue) ----------------
__device__ __forceinline__ void gemm_proj_body(const ushort* __restrict__ A,
                                               const ushort* __restrict__ B,
                                               ushort* __restrict__ C,
                                               const float* __restrict__ bias,
                                               int N, int K, int bx, int by) {
    __shared__ ushort lA[128 * 32];
    __shared__ ushort lB[128 * 32];
    const int tid = threadIdx.x;
    const int wave = tid >> 6, lane = tid & 63;
    const int i0 = by * 128, j0 = bx * 128;
    const int wm = wave >> 1, wn = wave & 1;

    f32x4 acc[4][4];
    f32x4 zero = {0.f, 0.f, 0.f, 0.f};
#pragma unroll
    for (int m = 0; m < 4; m++)
#pragma unroll
        for (int n = 0; n < 4; n++) acc[m][n] = zero;

    const int rs = wave * 16 + (lane >> 2);
    const int cbyte = (lane & 3) * 16;
    const char* gA1 = (const char*)(A + (size_t)(i0 + rs) * K) + cbyte;
    const char* gA2 = (const char*)(A + (size_t)(i0 + rs + 64) * K) + cbyte;
    const char* gB1 = (const char*)(B + (size_t)(j0 + rs) * K) + cbyte;
    const char* gB2 = (const char*)(B + (size_t)(j0 + rs + 64) * K) + cbyte;
    char* lA1 = (char*)lA + wave * 1024;
    char* lA2 = lA1 + 4096;
    char* lB1 = (char*)lB + wave * 1024;
    char* lB2 = lB1 + 4096;

    const int fr = lane & 15, fk = (lane >> 4) * 8;
    const ushort* pA = lA + (wm * 64 + fr) * 32 + fk;
    const ushort* pB = lB + (wn * 64 + fr) * 32 + fk;

    for (int kt = 0; kt < K / 32; ++kt) {
        load_lds16(gA1, lA1);
        load_lds16(gA2, lA2);
        load_lds16(gB1, lB1);
        load_lds16(gB2, lB2);
        gA1 += 64; gA2 += 64; gB1 += 64; gB2 += 64;
        __syncthreads();
        bf16x8 af[4], bv[4];
#pragma unroll
        for (int m = 0; m < 4; m++) af[m] = *(const bf16x8*)(pA + m * 16 * 32);
#pragma unroll
        for (int n = 0; n < 4; n++) bv[n] = *(const bf16x8*)(pB + n * 16 * 32);
#pragma unroll
        for (int m = 0; m < 4; m++)
#pragma unroll
            for (int n = 0; n < 4; n++)
                acc[m][n] = __builtin_amdgcn_mfma_f32_16x16x32_bf16(af[m], bv[n], acc[m][n], 0, 0, 0);
        __syncthreads();
    }

    const int fq = lane >> 4;
    const int r0 = i0 + wm * 64, c0 = j0 + wn * 64;
#pragma unroll
    for (int m = 0; m < 4; m++)
#pragma unroll
        for (int n = 0; n < 4; n++) {
            const int c = c0 + n * 16 + fr;
            const float badd = bias[c];
#pragma unroll
            for (int vv = 0; vv < 4; ++vv) {
                const int r = r0 + m * 16 + fq * 4 + vv;
                C[(size_t)r * N + c] = f2bf(acc[m][n][vv] + badd);
            }
        }
}

__global__ __launch_bounds__(256) void gemm_proj(
    const ushort* qb, const ushort* kb, const ushort* vb,
    const ushort* wq, const ushort* wk, const ushort* wv,
    const float* bq, const float* bk, const float* bv,
    ushort* Qp, ushort* Kp, ushort* Vp) {
    const ushort* A; const ushort* B; const float* bias; ushort* C;
    if (blockIdx.z == 0)      { A = qb; B = wq; bias = bq; C = Qp; }
    else if (blockIdx.z == 1) { A = kb; B = wk; bias = bk; C = Kp; }
    else                      { A = vb; B = wv; bias = bv; C = Vp; }
    const int lg = xcd_swizzle(blockIdx.x, 256);
    gemm_proj_body(A, B, C, bias, DIM, DIM, lg & 7, lg >> 3);
}

// ---------------- small fixup kernels ----------------
__global__ void reduce_add3(const float* __restrict__ p, float* __restrict__ out) {
    const size_t stride = (size_t)NQQ * DIM;
    const size_t i = ((size_t)blockIdx.x * 256 + threadIdx.x) * 4;
    float4 o = *(const float4*)(out + i);
    float4 a = *(const float4*)(p + i);
    float4 b = *(const float4*)(p + stride + i);
    float4 c = *(const float4*)(p + 2 * stride + i);
    o.x += a.x + b.x + c.x;
    o.y += a.y + b.y + c.y;
    o.z += a.z + b.z + c.z;
    o.w += a.w + b.w + c.w;
    *(float4*)(out + i) = o;
}

__global__ void colsum_combine(const float* __restrict__ cpart, float* __restrict__ cinv) {
    const int j = blockIdx.x * 256 + threadIdx.x;
    float s = 0;
    for (int c = 0; c < 16; ++c) s += cpart[(size_t)c * NKK + j];
    cinv[j] = 1.0f / s;
}

__global__ void scale_transpose(const ushort* __restrict__ Vp, const float* __restrict__ cinv,
                                ushort* __restrict__ Vt) {
    __shared__ ushort t[64][66];
    const int j0 = blockIdx.x * 64, d0 = blockIdx.y * 64;
    const int c = threadIdx.x & 63, rb = threadIdx.x >> 6;
#pragma unroll
    for (int i = 0; i < 16; ++i) {
        const int r = i * 4 + rb;
        const float inv = cinv[j0 + r];
        t[r][c] = f2bf(bf2f(Vp[(size_t)(j0 + r) * DIM + d0 + c]) * inv);
    }
    __syncthreads();
#pragma unroll
    for (int i = 0; i < 16; ++i) {
        const int r = i * 4 + rb;
        Vt[(size_t)(d0 + r) * NKK + j0 + c] = t[c][r];
    }
}

extern "C" void kernel_launch(void* const* d_in, const int* in_sizes, int n_in,
                              void* d_out, int out_size, void* d_ws, size_t ws_size,
                              hipStream_t stream) {
    const float* q  = (const float*)d_in[0];
    const float* k  = (const float*)d_in[1];
    const float* v  = (const float*)d_in[2];
    const float* Wq = (const float*)d_in[3];
    const float* bq = (const float*)d_in[4];
    const float* Wk = (const float*)d_in[5];
    const float* bk = (const float*)d_in[6];
    const float* Wv = (const float*)d_in[7];
    const float* bv = (const float*)d_in[8];
    float* out = (float*)d_out;

    char* ws = (char*)d_ws;
    size_t off = 0;
    auto alloc = [&](size_t b) { char* p = ws + off; off += (b + 255) & ~(size_t)255; return p; };
    // persistent region
    ushort* E     = (ushort*)alloc((size_t)NQQ * NKK * 2);      // 32 MB
    ushort* Vt    = (ushort*)alloc((size_t)DIM * NKK * 2);      //  8 MB
    float*  cpart = (float*)alloc((size_t)16 * NKK * 4);        // 256 KB
    float*  cinv  = (float*)alloc((size_t)NKK * 4);
    // temp region (dead before gemm8_out) aliased by `partial`
    char* tempBase = ws + off;
    ushort* qb  = (ushort*)alloc((size_t)NQQ * DIM * 2);
    ushort* kb  = (ushort*)alloc((size_t)NKK * DIM * 2);
    ushort* vb  = (ushort*)alloc((size_t)NKK * DIM * 2);
    ushort* wqb = (ushort*)alloc((size_t)DIM * DIM * 2);
    ushort* wkb = (ushort*)alloc((size_t)DIM * DIM * 2);
    ushort* wvb = (ushort*)alloc((size_t)DIM * DIM * 2);
    ushort* Qp  = (ushort*)alloc((size_t)NQQ * DIM * 2);
    ushort* Kp  = (ushort*)alloc((size_t)NKK * DIM * 2);
    ushort* Vp  = (ushort*)alloc((size_t)NKK * DIM * 2);
    float* partial = (float*)tempBase;                          // 48 MB alias
    (void)ws_size; (void)in_sizes; (void)n_in; (void)out_size;

    const int SMEM = 131072;
    hipFuncSetAttribute((const void*)gemm8_scores, hipFuncAttributeMaxDynamicSharedMemorySize, SMEM);
    hipFuncSetAttribute((const void*)gemm8_out, hipFuncAttributeMaxDynamicSharedMemorySize, SMEM);

    const int nqd = NQQ * DIM;
    const int ndd = DIM * DIM;
    cvt3_f32_bf16<<<dim3(nqd / 1024, 1, 3), 256, 0, stream>>>(q, k, v, qb, kb, vb, nqd);
    cvt3_f32_bf16<<<dim3(ndd / 1024, 1, 3), 256, 0, stream>>>(Wq, Wk, Wv, wqb, wkb, wvb, ndd);

    gemm_proj<<<dim3(256, 1, 3), 256, 0, stream>>>(
        qb, kb, vb, wqb, wkb, wvb, bq, bk, bv, Qp, Kp, Vp);

    gemm8_scores<<<dim3(256), 512, SMEM, stream>>>(Qp, Kp, E, cpart);

    colsum_combine<<<NKK / 256, 256, 0, stream>>>(cpart, cinv);

    scale_transpose<<<dim3(NKK / 64, DIM / 64), 256, 0, stream>>>(Vp, cinv, Vt);

    gemm8_out<<<dim3(64, 1, 4), 512, SMEM, stream>>>(E, Vt, out, partial);

    reduce_add3<<<nqd / 1024, 256, 0, stream>>>(partial, out);
}

// Round 7
// 142.252 us; speedup vs baseline: 1.4837x; 1.0416x over previous
//
#include <hip/hip_runtime.h>
#include <stdint.h>

#define NQQ 4096
#define NKK 4096
#define DIM 1024

typedef __attribute__((ext_vector_type(4))) float f32x4;
typedef __attribute__((ext_vector_type(8))) short bf16x8;

__device__ __forceinline__ float bf2f(ushort u) {
    union { uint32_t u; float f; } x; x.u = ((uint32_t)u) << 16; return x.f;
}
__device__ __forceinline__ ushort f2bf(float f) {
    union { float f; uint32_t u; } x; x.f = f;
    uint32_t u = x.u;
    return (ushort)((u + 0x7FFFu + ((u >> 16) & 1u)) >> 16);  // RNE
}

typedef const uint32_t __attribute__((address_space(1)))* as1_u32;
typedef uint32_t __attribute__((address_space(3)))* as3_u32;

__device__ __forceinline__ void load_lds16(const void* g, void* l) {
    __builtin_amdgcn_global_load_lds((as1_u32)(uintptr_t)g, (as3_u32)(uintptr_t)l, 16, 0, 0);
}

// XCD-aware chunked swizzle (bijective: nwg % 8 == 0 in all uses).
__device__ __forceinline__ int xcd_swizzle(int orig, int nwg) {
    const int q = nwg >> 3;
    return (orig & 7) * q + (orig >> 3);
}

// barrier + compiler memory-motion fence (keeps LDS ops inside their phase)
#define BARM() do { __builtin_amdgcn_s_barrier(); asm volatile("" ::: "memory"); } while (0)

// ---------------- fused fp32 -> bf16 convert (3 arrays per launch) ----------------
__global__ void cvt3_f32_bf16(const float* __restrict__ a, const float* __restrict__ b,
                              const float* __restrict__ c,
                              ushort* __restrict__ oa, ushort* __restrict__ ob,
                              ushort* __restrict__ oc, int n) {
    const float* x; ushort* y;
    if (blockIdx.z == 0)      { x = a; y = oa; }
    else if (blockIdx.z == 1) { x = b; y = ob; }
    else                      { x = c; y = oc; }
    int i = (blockIdx.x * blockDim.x + threadIdx.x) * 4;
    if (i + 3 < n) {
        float4 v = *(const float4*)(x + i);
        ushort4 o;
        o.x = f2bf(v.x); o.y = f2bf(v.y); o.z = f2bf(v.z); o.w = f2bf(v.w);
        *(ushort4*)(y + i) = o;
    }
}

// ================= 256x256 8-phase GEMM template (NT kernel) =================
// C[i,j] = sum_k A[i,k]*B[j,k].  BK=64, 8 waves (2M x 4N), 2-deep LDS dbuf,
// 3-bit 16B-granule XOR swizzle, fragment pipelining (B1 prefetch in ph(0,0),
// A1 prefetch at end of ph(0,1), B0 live across tile), compiler-counted lgkm
// waits, counted vmcnt at tile boundary, setprio around MFMA.
// EPI: 0 = +bias -> bf16, 1 = exp(x*scale)->bf16 + column sums, 2 = fp32 raw.
template <int EPI>
__device__ __forceinline__ void gemm8_body(const ushort* __restrict__ A,
                                           const ushort* __restrict__ B,
                                           void* __restrict__ Cv,
                                           const float* __restrict__ bias,
                                           float* __restrict__ cs,
                                           int N, int Kstride, int NT, size_t k0e,
                                           float scale, int i0, int j0, int csrow) {
    extern __shared__ char sm[];   // 131072
    const int tid = threadIdx.x;
    const int w = tid >> 6, l = tid & 63;
    const int wm = w >> 2, wn = w & 3;            // 2M x 4N waves
    const int fr = l & 15, fq = l >> 4;
    const size_t KB = (size_t)Kstride * 2;        // row stride bytes

    // swizzled read offset: row fr (+16m), col byte (fq*16 ^ (row&7)*16) [^ ks*64]
    const int aoff = fr * 128 + ((fq * 16) ^ ((l & 7) * 16));
    // stage lane constants: rows 16w+(l>>3)(+8); inverse-swizzled source col
    const int stRow = (w << 4) + (l >> 3);
    const int stColByte = ((l & 7) ^ (l >> 3)) << 4;

    f32x4 acc[8][4];
    f32x4 zero = {0.f, 0.f, 0.f, 0.f};
#pragma unroll
    for (int m = 0; m < 8; ++m)
#pragma unroll
        for (int n = 0; n < 4; ++n) acc[m][n] = zero;

    const char* Ab = (const char*)A;
    const char* Bb = (const char*)B;

    // stage one half-tile (ab: 0=A 1=B, h: half) of K-tile t into buffer buf
    auto stage = [&](int buf, int ab, int h, int t) {
        const char* src = ab ? Bb : Ab;
        const int rb = ab ? j0 : i0;
        const char* g = src + (size_t)(rb + h * 128 + stRow) * KB
                        + (k0e + (size_t)t * 64) * 2 + stColByte;
        char* d = sm + buf * 65536 + ab * 32768 + h * 16384 + (w * 2) * 1024;
        load_lds16(g, d);
        load_lds16(g + 8 * KB, d + 1024);
    };

    // prologue: tile0 all 4 halves + tile1.A0 + tile1.B1
    stage(0, 0, 0, 0); stage(0, 0, 1, 0); stage(0, 1, 0, 0); stage(0, 1, 1, 0);
    stage(1, 0, 0, 1); stage(1, 1, 1, 1);
    asm volatile("s_waitcnt vmcnt(4)" ::: "memory");   // tile0 landed; 2 half-tiles in flight
    BARM();

    bf16x8 a[4][2];        // current A quadrant (A0 then A1)
    bf16x8 b0f[2][2];      // B ch=0 frags, live across whole tile
    bf16x8 b1f[2][2];      // B ch=1 frags

    auto readA = [&](int buf, int rh) {
        const char* ba = sm + buf * 65536 + rh * 16384 + wm * 8192;
#pragma unroll
        for (int m = 0; m < 4; ++m)
#pragma unroll
            for (int ks = 0; ks < 2; ++ks)
                a[m][ks] = *(const bf16x8*)(ba + m * 2048 + (aoff ^ (ks * 64)));
    };
    auto readB = [&](int buf, int ch, bf16x8 (&bf)[2][2]) {
        const char* bb = sm + buf * 65536 + 32768 + ch * 16384 + wn * 4096;
#pragma unroll
        for (int n = 0; n < 2; ++n)
#pragma unroll
            for (int ks = 0; ks < 2; ++ks)
                bf[n][ks] = *(const bf16x8*)(bb + n * 2048 + (aoff ^ (ks * 64)));
    };
    auto mfmaQ = [&](int rh, int ch, bf16x8 (&bf)[2][2]) {
        __builtin_amdgcn_s_setprio(1);
#pragma unroll
        for (int m = 0; m < 4; ++m)
#pragma unroll
            for (int n = 0; n < 2; ++n)
#pragma unroll
                for (int ks = 0; ks < 2; ++ks)
                    acc[rh * 4 + m][ch * 2 + n] = __builtin_amdgcn_mfma_f32_16x16x32_bf16(
                        a[m][ks], bf[n][ks], acc[rh * 4 + m][ch * 2 + n], 0, 0, 0);
        __builtin_amdgcn_s_setprio(0);
    };

    // stages: t+1.A1 (ph00), t+1.B0 (ph01), t+2.A0 (ph11), t+2.B1 (ph10)
    for (int t = 0; t < NT; ++t) {
        const int buf = t & 1;
        const bool s1 = (t + 1) < NT, s2 = (t + 2) < NT;
        // ph(0,0): A0 x B0   (reads: A0, B0 self; B1 prefetch stays in flight)
        readA(buf, 0);
        readB(buf, 0, b0f);
        readB(buf, 1, b1f);
        if (s1) stage(buf ^ 1, 0, 1, t + 1);
        BARM();
        mfmaQ(0, 0, b0f);
        BARM();
        // ph(0,1): A0 x B1   (cached); prefetch A1 after last A0 use
        if (s1) stage(buf ^ 1, 1, 0, t + 1);
        BARM();
        mfmaQ(0, 1, b1f);
        readA(buf, 1);
        BARM();
        // ph(1,1): A1 x B1   (cached)
        if (s2) stage(buf, 0, 0, t + 2);
        BARM();
        mfmaQ(1, 1, b1f);
        BARM();
        // ph(1,0): A1 x B0   (cached)
        if (s2) stage(buf, 1, 1, t + 2);
        BARM();
        mfmaQ(1, 0, b0f);
        if (t < NT - 2)       asm volatile("s_waitcnt vmcnt(4)" ::: "memory");
        else if (t == NT - 2) asm volatile("s_waitcnt vmcnt(0)" ::: "memory");
        BARM();
    }

    // ---------------- epilogue ----------------
    if (EPI == 1) {
        float* csum = (float*)sm;   // LDS free after final loop barrier
        ushort* E = (ushort*)Cv;
        float cp[4] = {0.f, 0.f, 0.f, 0.f};
#pragma unroll
        for (int mi = 0; mi < 8; ++mi) {
            const int rg = i0 + (mi >> 2) * 128 + wm * 64 + (mi & 3) * 16 + fq * 4;
#pragma unroll
            for (int ni = 0; ni < 4; ++ni) {
                const int cg = j0 + (ni >> 1) * 128 + wn * 32 + (ni & 1) * 16 + fr;
#pragma unroll
                for (int r = 0; r < 4; ++r) {
                    const ushort ue = f2bf(__expf(acc[mi][ni][r] * scale));
                    E[(size_t)(rg + r) * N + cg] = ue;
                    cp[ni] += bf2f(ue);
                }
            }
        }
#pragma unroll
        for (int ni = 0; ni < 4; ++ni) {
            float s = cp[ni];
            s += __shfl_xor(s, 16);
            s += __shfl_xor(s, 32);
            if (fq == 0)
                csum[wm * 256 + (ni >> 1) * 128 + wn * 32 + (ni & 1) * 16 + fr] = s;
        }
        __syncthreads();
        if (tid < 256)
            cs[(size_t)csrow * NKK + j0 + tid] = csum[tid] + csum[256 + tid];
    } else if (EPI == 0) {
        ushort* C = (ushort*)Cv;
#pragma unroll
        for (int mi = 0; mi < 8; ++mi) {
            const int rg = i0 + (mi >> 2) * 128 + wm * 64 + (mi & 3) * 16 + fq * 4;
#pragma unroll
            for (int ni = 0; ni < 4; ++ni) {
                const int cg = j0 + (ni >> 1) * 128 + wn * 32 + (ni & 1) * 16 + fr;
                const float badd = bias[cg];
#pragma unroll
                for (int r = 0; r < 4; ++r)
                    C[(size_t)(rg + r) * N + cg] = f2bf(acc[mi][ni][r] + badd);
            }
        }
    } else {
        float* O = (float*)Cv;
#pragma unroll
        for (int mi = 0; mi < 8; ++mi) {
            const int rg = i0 + (mi >> 2) * 128 + wm * 64 + (mi & 3) * 16 + fq * 4;
#pragma unroll
            for (int ni = 0; ni < 4; ++ni) {
                const int cg = j0 + (ni >> 1) * 128 + wn * 32 + (ni & 1) * 16 + fr;
#pragma unroll
                for (int r = 0; r < 4; ++r)
                    O[(size_t)(rg + r) * N + cg] = acc[mi][ni][r];
            }
        }
    }
}

__global__ __launch_bounds__(512, 2) void gemm8_proj(
    const ushort* __restrict__ qb, const ushort* __restrict__ kb,
    const ushort* __restrict__ vb,
    const ushort* __restrict__ wq, const ushort* __restrict__ wk,
    const ushort* __restrict__ wv,
    const float* __restrict__ bq, const float* __restrict__ bk,
    const float* __restrict__ bv,
    ushort* __restrict__ Qp, ushort* __restrict__ Kp, ushort* __restrict__ Vp) {
    const ushort* A; const ushort* B; const float* bias; ushort* C;
    if (blockIdx.z == 0)      { A = qb; B = wq; bias = bq; C = Qp; }
    else if (blockIdx.z == 1) { A = kb; B = wk; bias = bk; C = Kp; }
    else                      { A = vb; B = wv; bias = bv; C = Vp; }
    const int b = xcd_swizzle(blockIdx.x, 64);
    const int tx = b & 3, ty = b >> 2;
    gemm8_body<0>(A, B, C, bias, nullptr, DIM, DIM, 16, 0, 1.0f,
                  ty * 256, tx * 256, 0);
}

__global__ __launch_bounds__(512, 2) void gemm8_scores(const ushort* __restrict__ Qp,
                                                       const ushort* __restrict__ Kp,
                                                       ushort* __restrict__ E,
                                                       float* __restrict__ cpart) {
    const int b = xcd_swizzle(blockIdx.x, 256);
    const int tx = b & 15, ty = b >> 4;
    gemm8_body<1>(Qp, Kp, E, nullptr, cpart, NKK, DIM, 16, 0, 1.0f / 4096.0f,
                  ty * 256, tx * 256, ty);
}

__global__ __launch_bounds__(512, 2) void gemm8_out(const ushort* __restrict__ E,
                                                    const ushort* __restrict__ Vt,
                                                    float* __restrict__ out,
                                                    float* __restrict__ partial) {
    const int s = blockIdx.z;
    float* C = (s == 0) ? out : (partial + (size_t)(s - 1) * NQQ * DIM);
    const int b = xcd_swizzle(blockIdx.x, 64);
    const int tx = b & 3, ty = b >> 2;
    gemm8_body<2>(E, Vt, C, nullptr, nullptr, DIM, NKK, 16, (size_t)s * 1024, 1.0f,
                  ty * 256, tx * 256, 0);
}

// ---------------- small fixup kernels ----------------
__global__ void reduce_add3(const float* __restrict__ p, float* __restrict__ out) {
    const size_t stride = (size_t)NQQ * DIM;
    const size_t i = ((size_t)blockIdx.x * 256 + threadIdx.x) * 4;
    float4 o = *(const float4*)(out + i);
    float4 a = *(const float4*)(p + i);
    float4 b = *(const float4*)(p + stride + i);
    float4 c = *(const float4*)(p + 2 * stride + i);
    o.x += a.x + b.x + c.x;
    o.y += a.y + b.y + c.y;
    o.z += a.z + b.z + c.z;
    o.w += a.w + b.w + c.w;
    *(float4*)(out + i) = o;
}

__global__ void colsum_combine(const float* __restrict__ cpart, float* __restrict__ cinv) {
    const int j = blockIdx.x * 256 + threadIdx.x;
    float s = 0;
    for (int c = 0; c < 16; ++c) s += cpart[(size_t)c * NKK + j];
    cinv[j] = 1.0f / s;
}

__global__ void scale_transpose(const ushort* __restrict__ Vp, const float* __restrict__ cinv,
                                ushort* __restrict__ Vt) {
    __shared__ ushort t[64][66];
    const int j0 = blockIdx.x * 64, d0 = blockIdx.y * 64;
    const int c = threadIdx.x & 63, rb = threadIdx.x >> 6;
#pragma unroll
    for (int i = 0; i < 16; ++i) {
        const int r = i * 4 + rb;
        const float inv = cinv[j0 + r];
        t[r][c] = f2bf(bf2f(Vp[(size_t)(j0 + r) * DIM + d0 + c]) * inv);
    }
    __syncthreads();
#pragma unroll
    for (int i = 0; i < 16; ++i) {
        const int r = i * 4 + rb;
        Vt[(size_t)(d0 + r) * NKK + j0 + c] = t[c][r];
    }
}

extern "C" void kernel_launch(void* const* d_in, const int* in_sizes, int n_in,
                              void* d_out, int out_size, void* d_ws, size_t ws_size,
                              hipStream_t stream) {
    const float* q  = (const float*)d_in[0];
    const float* k  = (const float*)d_in[1];
    const float* v  = (const float*)d_in[2];
    const float* Wq = (const float*)d_in[3];
    const float* bq = (const float*)d_in[4];
    const float* Wk = (const float*)d_in[5];
    const float* bk = (const float*)d_in[6];
    const float* Wv = (const float*)d_in[7];
    const float* bv = (const float*)d_in[8];
    float* out = (float*)d_out;

    char* ws = (char*)d_ws;
    size_t off = 0;
    auto alloc = [&](size_t b) { char* p = ws + off; off += (b + 255) & ~(size_t)255; return p; };
    // persistent region
    ushort* E     = (ushort*)alloc((size_t)NQQ * NKK * 2);      // 32 MB
    ushort* Vt    = (ushort*)alloc((size_t)DIM * NKK * 2);      //  8 MB
    float*  cpart = (float*)alloc((size_t)16 * NKK * 4);        // 256 KB
    float*  cinv  = (float*)alloc((size_t)NKK * 4);
    // temp region (dead before gemm8_out) aliased by `partial`
    char* tempBase = ws + off;
    ushort* qb  = (ushort*)alloc((size_t)NQQ * DIM * 2);
    ushort* kb  = (ushort*)alloc((size_t)NKK * DIM * 2);
    ushort* vb  = (ushort*)alloc((size_t)NKK * DIM * 2);
    ushort* wqb = (ushort*)alloc((size_t)DIM * DIM * 2);
    ushort* wkb = (ushort*)alloc((size_t)DIM * DIM * 2);
    ushort* wvb = (ushort*)alloc((size_t)DIM * DIM * 2);
    ushort* Qp  = (ushort*)alloc((size_t)NQQ * DIM * 2);
    ushort* Kp  = (ushort*)alloc((size_t)NKK * DIM * 2);
    ushort* Vp  = (ushort*)alloc((size_t)NKK * DIM * 2);
    float* partial = (float*)tempBase;                          // 48 MB alias
    (void)ws_size; (void)in_sizes; (void)n_in; (void)out_size;

    const int SMEM = 131072;
    hipFuncSetAttribute((const void*)gemm8_proj, hipFuncAttributeMaxDynamicSharedMemorySize, SMEM);
    hipFuncSetAttribute((const void*)gemm8_scores, hipFuncAttributeMaxDynamicSharedMemorySize, SMEM);
    hipFuncSetAttribute((const void*)gemm8_out, hipFuncAttributeMaxDynamicSharedMemorySize, SMEM);

    const int nqd = NQQ * DIM;
    const int ndd = DIM * DIM;
    cvt3_f32_bf16<<<dim3(nqd / 1024, 1, 3), 256, 0, stream>>>(q, k, v, qb, kb, vb, nqd);
    cvt3_f32_bf16<<<dim3(ndd / 1024, 1, 3), 256, 0, stream>>>(Wq, Wk, Wv, wqb, wkb, wvb, ndd);

    gemm8_proj<<<dim3(64, 1, 3), 512, SMEM, stream>>>(
        qb, kb, vb, wqb, wkb, wvb, bq, bk, bv, Qp, Kp, Vp);

    gemm8_scores<<<dim3(256), 512, SMEM, stream>>>(Qp, Kp, E, cpart);

    colsum_combine<<<NKK / 256, 256, 0, stream>>>(cpart, cinv);

    scale_transpose<<<dim3(NKK / 64, DIM / 64), 256, 0, stream>>>(Vp, cinv, Vt);

    gemm8_out<<<dim3(64, 1, 4), 512, SMEM, stream>>>(E, Vt, out, partial);

    reduce_add3<<<nqd / 1024, 256, 0, stream>>>(partial, out);
}

// Round 8
// 138.166 us; speedup vs baseline: 1.5276x; 1.0296x over previous
//
#include <hip/hip_runtime.h>
#include <stdint.h>

#define NQQ 4096
#define NKK 4096
#define DIM 1024

typedef __attribute__((ext_vector_type(4))) float f32x4;
typedef __attribute__((ext_vector_type(8))) short bf16x8;

__device__ __forceinline__ float bf2f(ushort u) {
    union { uint32_t u; float f; } x; x.u = ((uint32_t)u) << 16; return x.f;
}
__device__ __forceinline__ ushort f2bf(float f) {
    union { float f; uint32_t u; } x; x.f = f;
    uint32_t u = x.u;
    return (ushort)((u + 0x7FFFu + ((u >> 16) & 1u)) >> 16);  // RNE
}

typedef const uint32_t __attribute__((address_space(1)))* as1_u32;
typedef uint32_t __attribute__((address_space(3)))* as3_u32;

__device__ __forceinline__ void load_lds16(const void* g, void* l) {
    __builtin_amdgcn_global_load_lds((as1_u32)(uintptr_t)g, (as3_u32)(uintptr_t)l, 16, 0, 0);
}

// XCD-aware chunked swizzle (bijective: nwg % 8 == 0 in all uses).
__device__ __forceinline__ int xcd_swizzle(int orig, int nwg) {
    const int q = nwg >> 3;
    return (orig & 7) * q + (orig >> 3);
}

// barrier + compiler memory-motion fence (keeps LDS ops inside their phase)
#define BARM() do { __builtin_amdgcn_s_barrier(); asm volatile("" ::: "memory"); } while (0)

// ---------------- fused fp32 -> bf16 convert (3 arrays per launch) ----------------
__global__ void cvt3_f32_bf16(const float* __restrict__ a, const float* __restrict__ b,
                              const float* __restrict__ c,
                              ushort* __restrict__ oa, ushort* __restrict__ ob,
                              ushort* __restrict__ oc, int n) {
    const float* x; ushort* y;
    if (blockIdx.z == 0)      { x = a; y = oa; }
    else if (blockIdx.z == 1) { x = b; y = ob; }
    else                      { x = c; y = oc; }
    int i = (blockIdx.x * blockDim.x + threadIdx.x) * 4;
    if (i + 3 < n) {
        float4 v = *(const float4*)(x + i);
        ushort4 o;
        o.x = f2bf(v.x); o.y = f2bf(v.y); o.z = f2bf(v.z); o.w = f2bf(v.w);
        *(ushort4*)(y + i) = o;
    }
}

// ================= 256x256 4-barrier GEMM template (NT kernel) =================
// C[i,j] = sum_k A[i,k]*B[j,k].  BK=64, 8 waves (2M x 4N), 2-deep LDS dbuf,
// 3-bit 16B-granule XOR swizzle, fragment pipelining, ONE barrier per quadrant
// (slot-reuse audited against end-of-phase barriers only), counted vmcnt at
// tile boundary, setprio around MFMA.
// EPI: 0 = +bias -> bf16, 1 = exp(x*scale)->bf16 + column sums, 2 = fp32 raw.
template <int EPI>
__device__ __forceinline__ void gemm8_body(const ushort* __restrict__ A,
                                           const ushort* __restrict__ B,
                                           void* __restrict__ Cv,
                                           const float* __restrict__ bias,
                                           float* __restrict__ cs,
                                           int N, int Kstride, int NT, size_t k0e,
                                           float scale, int i0, int j0, int csrow) {
    extern __shared__ char sm[];   // 131072
    const int tid = threadIdx.x;
    const int w = tid >> 6, l = tid & 63;
    const int wm = w >> 2, wn = w & 3;            // 2M x 4N waves
    const int fr = l & 15, fq = l >> 4;
    const size_t KB = (size_t)Kstride * 2;        // row stride bytes

    // swizzled read offset: row fr (+16m), col byte (fq*16 ^ (row&7)*16) [^ ks*64]
    const int aoff = fr * 128 + ((fq * 16) ^ ((l & 7) * 16));
    // stage lane constants: rows 16w+(l>>3)(+8); inverse-swizzled source col
    const int stRow = (w << 4) + (l >> 3);
    const int stColByte = ((l & 7) ^ (l >> 3)) << 4;

    f32x4 acc[8][4];
    f32x4 zero = {0.f, 0.f, 0.f, 0.f};
#pragma unroll
    for (int m = 0; m < 8; ++m)
#pragma unroll
        for (int n = 0; n < 4; ++n) acc[m][n] = zero;

    const char* Ab = (const char*)A;
    const char* Bb = (const char*)B;

    // stage one half-tile (ab: 0=A 1=B, h: half) of K-tile t into buffer buf
    auto stage = [&](int buf, int ab, int h, int t) {
        const char* src = ab ? Bb : Ab;
        const int rb = ab ? j0 : i0;
        const char* g = src + (size_t)(rb + h * 128 + stRow) * KB
                        + (k0e + (size_t)t * 64) * 2 + stColByte;
        char* d = sm + buf * 65536 + ab * 32768 + h * 16384 + (w * 2) * 1024;
        load_lds16(g, d);
        load_lds16(g + 8 * KB, d + 1024);
    };

    // prologue: tile0 all 4 halves + tile1.A0 + tile1.B1
    stage(0, 0, 0, 0); stage(0, 0, 1, 0); stage(0, 1, 0, 0); stage(0, 1, 1, 0);
    stage(1, 0, 0, 1); stage(1, 1, 1, 1);
    asm volatile("s_waitcnt vmcnt(4)" ::: "memory");   // tile0 landed; 2 half-tiles in flight
    BARM();

    bf16x8 a[4][2];        // current A quadrant (A0 then A1)
    bf16x8 b0f[2][2];      // B ch=0 frags, live across whole tile
    bf16x8 b1f[2][2];      // B ch=1 frags

    auto readA = [&](int buf, int rh) {
        const char* ba = sm + buf * 65536 + rh * 16384 + wm * 8192;
#pragma unroll
        for (int m = 0; m < 4; ++m)
#pragma unroll
            for (int ks = 0; ks < 2; ++ks)
                a[m][ks] = *(const bf16x8*)(ba + m * 2048 + (aoff ^ (ks * 64)));
    };
    auto readB = [&](int buf, int ch, bf16x8 (&bf)[2][2]) {
        const char* bb = sm + buf * 65536 + 32768 + ch * 16384 + wn * 4096;
#pragma unroll
        for (int n = 0; n < 2; ++n)
#pragma unroll
            for (int ks = 0; ks < 2; ++ks)
                bf[n][ks] = *(const bf16x8*)(bb + n * 2048 + (aoff ^ (ks * 64)));
    };
    auto mfmaQ = [&](int rh, int ch, bf16x8 (&bf)[2][2]) {
        __builtin_amdgcn_s_setprio(1);
#pragma unroll
        for (int m = 0; m < 4; ++m)
#pragma unroll
            for (int n = 0; n < 2; ++n)
#pragma unroll
                for (int ks = 0; ks < 2; ++ks)
                    acc[rh * 4 + m][ch * 2 + n] = __builtin_amdgcn_mfma_f32_16x16x32_bf16(
                        a[m][ks], bf[n][ks], acc[rh * 4 + m][ch * 2 + n], 0, 0, 0);
        __builtin_amdgcn_s_setprio(0);
    };

    // Per tile: 4 phases, ONE barrier each.
    // stages: t+1.A1 (ph1), t+1.B0 (ph2), t+2.A0 (ph3), t+2.B1 (ph4)
    // Slot audit (end-of-phase barriers only):
    //   buf.A0/B0: read ph1, block-wide done by ph1-end -> stage t+2.A0 at ph3 OK
    //   buf.B1:   read ph1, done by ph2-end (lgkm at ph2 MFMA) -> stage t+2.B1 ph4 OK
    //   buf^1.A1: read by t-1 at its ph2, done by t-1 ph3-end -> stage t.ph1 OK
    //   buf^1.B0: read by t-1 ph1, done by t-1 ph1-end -> stage t.ph2 OK
    for (int t = 0; t < NT; ++t) {
        const int buf = t & 1;
        const bool s1 = (t + 1) < NT, s2 = (t + 2) < NT;
        // ph1: A0 x B0  (reads A0,B0,B1; lgkm before MFMA counts only A0,B0)
        readA(buf, 0);
        readB(buf, 0, b0f);
        readB(buf, 1, b1f);
        if (s1) stage(buf ^ 1, 0, 1, t + 1);
        mfmaQ(0, 0, b0f);
        BARM();
        // ph2: A0 x B1  (cached); A1 read after last A0 use, hides under ph3
        if (s1) stage(buf ^ 1, 1, 0, t + 1);
        mfmaQ(0, 1, b1f);
        readA(buf, 1);
        BARM();
        // ph3: A1 x B1  (cached)
        if (s2) stage(buf, 0, 0, t + 2);
        mfmaQ(1, 1, b1f);
        BARM();
        // ph4: A1 x B0  (cached)
        if (s2) stage(buf, 1, 1, t + 2);
        mfmaQ(1, 0, b0f);
        if (t < NT - 2)       asm volatile("s_waitcnt vmcnt(4)" ::: "memory");
        else if (t == NT - 2) asm volatile("s_waitcnt vmcnt(0)" ::: "memory");
        BARM();
    }

    // ---------------- epilogue ----------------
    if (EPI == 1) {
        float* csum = (float*)sm;   // LDS free after final loop barrier
        ushort* E = (ushort*)Cv;
        float cp[4] = {0.f, 0.f, 0.f, 0.f};
#pragma unroll
        for (int mi = 0; mi < 8; ++mi) {
            const int rg = i0 + (mi >> 2) * 128 + wm * 64 + (mi & 3) * 16 + fq * 4;
#pragma unroll
            for (int ni = 0; ni < 4; ++ni) {
                const int cg = j0 + (ni >> 1) * 128 + wn * 32 + (ni & 1) * 16 + fr;
#pragma unroll
                for (int r = 0; r < 4; ++r) {
                    const ushort ue = f2bf(__expf(acc[mi][ni][r] * scale));
                    E[(size_t)(rg + r) * N + cg] = ue;
                    cp[ni] += bf2f(ue);
                }
            }
        }
#pragma unroll
        for (int ni = 0; ni < 4; ++ni) {
            float s = cp[ni];
            s += __shfl_xor(s, 16);
            s += __shfl_xor(s, 32);
            if (fq == 0)
                csum[wm * 256 + (ni >> 1) * 128 + wn * 32 + (ni & 1) * 16 + fr] = s;
        }
        __syncthreads();
        if (tid < 256)
            cs[(size_t)csrow * NKK + j0 + tid] = csum[tid] + csum[256 + tid];
    } else if (EPI == 0) {
        ushort* C = (ushort*)Cv;
#pragma unroll
        for (int mi = 0; mi < 8; ++mi) {
            const int rg = i0 + (mi >> 2) * 128 + wm * 64 + (mi & 3) * 16 + fq * 4;
#pragma unroll
            for (int ni = 0; ni < 4; ++ni) {
                const int cg = j0 + (ni >> 1) * 128 + wn * 32 + (ni & 1) * 16 + fr;
                const float badd = bias[cg];
#pragma unroll
                for (int r = 0; r < 4; ++r)
                    C[(size_t)(rg + r) * N + cg] = f2bf(acc[mi][ni][r] + badd);
            }
        }
    } else {
        float* O = (float*)Cv;
#pragma unroll
        for (int mi = 0; mi < 8; ++mi) {
            const int rg = i0 + (mi >> 2) * 128 + wm * 64 + (mi & 3) * 16 + fq * 4;
#pragma unroll
            for (int ni = 0; ni < 4; ++ni) {
                const int cg = j0 + (ni >> 1) * 128 + wn * 32 + (ni & 1) * 16 + fr;
#pragma unroll
                for (int r = 0; r < 4; ++r)
                    O[(size_t)(rg + r) * N + cg] = acc[mi][ni][r];
            }
        }
    }
}

__global__ __launch_bounds__(512, 2) void gemm8_proj(
    const ushort* __restrict__ qb, const ushort* __restrict__ kb,
    const ushort* __restrict__ vb,
    const ushort* __restrict__ wq, const ushort* __restrict__ wk,
    const ushort* __restrict__ wv,
    const float* __restrict__ bq, const float* __restrict__ bk,
    const float* __restrict__ bv,
    ushort* __restrict__ Qp, ushort* __restrict__ Kp, ushort* __restrict__ Vp) {
    const ushort* A; const ushort* B; const float* bias; ushort* C;
    if (blockIdx.z == 0)      { A = qb; B = wq; bias = bq; C = Qp; }
    else if (blockIdx.z == 1) { A = kb; B = wk; bias = bk; C = Kp; }
    else                      { A = vb; B = wv; bias = bv; C = Vp; }
    const int b = xcd_swizzle(blockIdx.x, 64);
    const int tx = b & 3, ty = b >> 2;
    gemm8_body<0>(A, B, C, bias, nullptr, DIM, DIM, 16, 0, 1.0f,
                  ty * 256, tx * 256, 0);
}

__global__ __launch_bounds__(512, 2) void gemm8_scores(const ushort* __restrict__ Qp,
                                                       const ushort* __restrict__ Kp,
                                                       ushort* __restrict__ E,
                                                       float* __restrict__ cpart) {
    const int b = xcd_swizzle(blockIdx.x, 256);
    const int tx = b & 15, ty = b >> 4;
    gemm8_body<1>(Qp, Kp, E, nullptr, cpart, NKK, DIM, 16, 0, 1.0f / 4096.0f,
                  ty * 256, tx * 256, ty);
}

__global__ __launch_bounds__(512, 2) void gemm8_out(const ushort* __restrict__ E,
                                                    const ushort* __restrict__ Vt,
                                                    float* __restrict__ out,
                                                    float* __restrict__ partial) {
    const int s = blockIdx.z;
    float* C = (s == 0) ? out : (partial + (size_t)(s - 1) * NQQ * DIM);
    const int b = xcd_swizzle(blockIdx.x, 64);
    const int tx = b & 3, ty = b >> 2;
    gemm8_body<2>(E, Vt, C, nullptr, nullptr, DIM, NKK, 16, (size_t)s * 1024, 1.0f,
                  ty * 256, tx * 256, 0);
}

// ---------------- small fixup kernels ----------------
__global__ void reduce_add3(const float* __restrict__ p, float* __restrict__ out) {
    const size_t stride = (size_t)NQQ * DIM;
    const size_t i = ((size_t)blockIdx.x * 256 + threadIdx.x) * 4;
    float4 o = *(const float4*)(out + i);
    float4 a = *(const float4*)(p + i);
    float4 b = *(const float4*)(p + stride + i);
    float4 c = *(const float4*)(p + 2 * stride + i);
    o.x += a.x + b.x + c.x;
    o.y += a.y + b.y + c.y;
    o.z += a.z + b.z + c.z;
    o.w += a.w + b.w + c.w;
    *(float4*)(out + i) = o;
}

__global__ void colsum_combine(const float* __restrict__ cpart, float* __restrict__ cinv) {
    const int j = blockIdx.x * 256 + threadIdx.x;
    float s = 0;
    for (int c = 0; c < 16; ++c) s += cpart[(size_t)c * NKK + j];
    cinv[j] = 1.0f / s;
}

__global__ void scale_transpose(const ushort* __restrict__ Vp, const float* __restrict__ cinv,
                                ushort* __restrict__ Vt) {
    __shared__ ushort t[64][66];
    const int j0 = blockIdx.x * 64, d0 = blockIdx.y * 64;
    const int c = threadIdx.x & 63, rb = threadIdx.x >> 6;
#pragma unroll
    for (int i = 0; i < 16; ++i) {
        const int r = i * 4 + rb;
        const float inv = cinv[j0 + r];
        t[r][c] = f2bf(bf2f(Vp[(size_t)(j0 + r) * DIM + d0 + c]) * inv);
    }
    __syncthreads();
#pragma unroll
    for (int i = 0; i < 16; ++i) {
        const int r = i * 4 + rb;
        Vt[(size_t)(d0 + r) * NKK + j0 + c] = t[c][r];
    }
}

extern "C" void kernel_launch(void* const* d_in, const int* in_sizes, int n_in,
                              void* d_out, int out_size, void* d_ws, size_t ws_size,
                              hipStream_t stream) {
    const float* q  = (const float*)d_in[0];
    const float* k  = (const float*)d_in[1];
    const float* v  = (const float*)d_in[2];
    const float* Wq = (const float*)d_in[3];
    const float* bq = (const float*)d_in[4];
    const float* Wk = (const float*)d_in[5];
    const float* bk = (const float*)d_in[6];
    const float* Wv = (const float*)d_in[7];
    const float* bv = (const float*)d_in[8];
    float* out = (float*)d_out;

    char* ws = (char*)d_ws;
    size_t off = 0;
    auto alloc = [&](size_t b) { char* p = ws + off; off += (b + 255) & ~(size_t)255; return p; };
    // persistent region
    ushort* E     = (ushort*)alloc((size_t)NQQ * NKK * 2);      // 32 MB
    ushort* Vt    = (ushort*)alloc((size_t)DIM * NKK * 2);      //  8 MB
    float*  cpart = (float*)alloc((size_t)16 * NKK * 4);        // 256 KB
    float*  cinv  = (float*)alloc((size_t)NKK * 4);
    // temp region (dead before gemm8_out) aliased by `partial`
    char* tempBase = ws + off;
    ushort* qb  = (ushort*)alloc((size_t)NQQ * DIM * 2);
    ushort* kb  = (ushort*)alloc((size_t)NKK * DIM * 2);
    ushort* vb  = (ushort*)alloc((size_t)NKK * DIM * 2);
    ushort* wqb = (ushort*)alloc((size_t)DIM * DIM * 2);
    ushort* wkb = (ushort*)alloc((size_t)DIM * DIM * 2);
    ushort* wvb = (ushort*)alloc((size_t)DIM * DIM * 2);
    ushort* Qp  = (ushort*)alloc((size_t)NQQ * DIM * 2);
    ushort* Kp  = (ushort*)alloc((size_t)NKK * DIM * 2);
    ushort* Vp  = (ushort*)alloc((size_t)NKK * DIM * 2);
    float* partial = (float*)tempBase;                          // 48 MB alias
    (void)ws_size; (void)in_sizes; (void)n_in; (void)out_size;

    const int SMEM = 131072;
    hipFuncSetAttribute((const void*)gemm8_proj, hipFuncAttributeMaxDynamicSharedMemorySize, SMEM);
    hipFuncSetAttribute((const void*)gemm8_scores, hipFuncAttributeMaxDynamicSharedMemorySize, SMEM);
    hipFuncSetAttribute((const void*)gemm8_out, hipFuncAttributeMaxDynamicSharedMemorySize, SMEM);

    const int nqd = NQQ * DIM;
    const int ndd = DIM * DIM;
    cvt3_f32_bf16<<<dim3(nqd / 1024, 1, 3), 256, 0, stream>>>(q, k, v, qb, kb, vb, nqd);
    cvt3_f32_bf16<<<dim3(ndd / 1024, 1, 3), 256, 0, stream>>>(Wq, Wk, Wv, wqb, wkb, wvb, ndd);

    gemm8_proj<<<dim3(64, 1, 3), 512, SMEM, stream>>>(
        qb, kb, vb, wqb, wkb, wvb, bq, bk, bv, Qp, Kp, Vp);

    gemm8_scores<<<dim3(256), 512, SMEM, stream>>>(Qp, Kp, E, cpart);

    colsum_combine<<<NKK / 256, 256, 0, stream>>>(cpart, cinv);

    scale_transpose<<<dim3(NKK / 64, DIM / 64), 256, 0, stream>>>(Vp, cinv, Vt);

    gemm8_out<<<dim3(64, 1, 4), 512, SMEM, stream>>>(E, Vt, out, partial);

    reduce_add3<<<nqd / 1024, 256, 0, stream>>>(partial, out);
}